// Round 1
// baseline (1250.348 us; speedup 1.0000x reference)
//
#include <hip/hip_runtime.h>
#include <math.h>

// GAT 2-layer, MI355X. All f32.
// Sizes fixed per reference.
#define NN 50000
#define NE 800000
#define ET 850000          // NE + NN self loops
#define DIN 512
#define F1 128             // HEADS*HIDDEN
#define NC 40
#define NEG 0.2f

__device__ inline float atomicMaxF(float* addr, float val) {
    if (val >= 0.f)
        return __int_as_float(atomicMax((int*)addr, __float_as_int(val)));
    else
        return __uint_as_float(atomicMin((unsigned int*)addr, __float_as_uint(val)));
}

__global__ void fill_kernel(float* __restrict__ p, long n, float v) {
    long i = (long)blockIdx.x * blockDim.x + threadIdx.x;
    if (i < n) p[i] = v;
}

// ---------------- GEMM1: [NN,512] x [512,128] -> hpre [NN,128] ----------------
__global__ __launch_bounds__(256) void gemm1_kernel(const float* __restrict__ X,
        const float* __restrict__ W, float* __restrict__ H) {
    __shared__ float As[64 * 33];
    __shared__ float Bs[32 * F1];
    const int tid  = threadIdx.x;
    const int row0 = blockIdx.x * 64;
    const int trow = tid >> 4;   // 0..15
    const int tcol = tid & 15;   // 0..15
    float acc[4][8];
    #pragma unroll
    for (int r = 0; r < 4; ++r)
        #pragma unroll
        for (int c = 0; c < 8; ++c) acc[r][c] = 0.f;

    for (int k0 = 0; k0 < DIN; k0 += 32) {
        #pragma unroll
        for (int j = 0; j < 2; ++j) {
            int idx = tid + j * 256;          // 512 float4 of A tile
            int r = idx >> 3, c = (idx & 7) << 2;
            int gr = row0 + r;
            float4 v = make_float4(0.f, 0.f, 0.f, 0.f);
            if (gr < NN) v = *(const float4*)(X + (long)gr * DIN + k0 + c);
            As[r * 33 + c + 0] = v.x;
            As[r * 33 + c + 1] = v.y;
            As[r * 33 + c + 2] = v.z;
            As[r * 33 + c + 3] = v.w;
        }
        #pragma unroll
        for (int j = 0; j < 4; ++j) {
            int idx = tid + j * 256;          // 1024 float4 of B tile
            int r = idx >> 5, c = (idx & 31) << 2;
            *(float4*)(&Bs[r * F1 + c]) = *(const float4*)(W + (k0 + r) * F1 + c);
        }
        __syncthreads();
        #pragma unroll
        for (int k = 0; k < 32; ++k) {
            float aa[4];
            #pragma unroll
            for (int r = 0; r < 4; ++r) aa[r] = As[(trow * 4 + r) * 33 + k];
            float4 b0 = *(const float4*)(&Bs[k * F1 + tcol * 8]);
            float4 b1 = *(const float4*)(&Bs[k * F1 + tcol * 8 + 4]);
            float bb[8] = {b0.x, b0.y, b0.z, b0.w, b1.x, b1.y, b1.z, b1.w};
            #pragma unroll
            for (int r = 0; r < 4; ++r)
                #pragma unroll
                for (int c = 0; c < 8; ++c)
                    acc[r][c] += aa[r] * bb[c];
        }
        __syncthreads();
    }
    #pragma unroll
    for (int r = 0; r < 4; ++r) {
        int gr = row0 + trow * 4 + r;
        if (gr < NN) {
            float4 o0 = make_float4(acc[r][0], acc[r][1], acc[r][2], acc[r][3]);
            float4 o1 = make_float4(acc[r][4], acc[r][5], acc[r][6], acc[r][7]);
            *(float4*)(H + (long)gr * F1 + tcol * 8)     = o0;
            *(float4*)(H + (long)gr * F1 + tcol * 8 + 4) = o1;
        }
    }
}

// ------------- per-node attention scores, layer 1: [NN,4] each -------------
__global__ void nscore1_kernel(const float* __restrict__ H,
                               const float* __restrict__ a_src,
                               const float* __restrict__ a_dst,
                               float* __restrict__ ssrc, float* __restrict__ sdst) {
    int i = blockIdx.x * blockDim.x + threadIdx.x;   // n*4 + h
    if (i >= NN * 4) return;
    int n = i >> 2, h = i & 3;
    const float* hp = H + (long)n * F1 + h * 32;
    float s1 = 0.f, s2 = 0.f;
    #pragma unroll
    for (int c = 0; c < 32; ++c) {
        float v = hp[c];
        s1 += v * a_src[h * 32 + c];
        s2 += v * a_dst[h * 32 + c];
    }
    ssrc[i] = s1;
    sdst[i] = s2;
}

// ------------- edge logits + segment max (layer 1, 4 heads) -------------
__global__ void edge_max1(const int* __restrict__ src, const int* __restrict__ dst,
                          const float* __restrict__ ssrc, const float* __restrict__ sdst,
                          float* __restrict__ el, float* __restrict__ m) {
    int e = blockIdx.x * blockDim.x + threadIdx.x;
    if (e >= ET) return;
    int s = (e < NE) ? src[e] : (e - NE);
    int d = (e < NE) ? dst[e] : (e - NE);
    float4 vs = *(const float4*)(ssrc + (long)s * 4);
    float4 vd = *(const float4*)(sdst + (long)d * 4);
    float v[4] = {vs.x + vd.x, vs.y + vd.y, vs.z + vd.z, vs.w + vd.w};
    #pragma unroll
    for (int h = 0; h < 4; ++h) {
        float x = v[h];
        x = (x > 0.f) ? x : NEG * x;
        el[(long)e * 4 + h] = x;
        atomicMaxF(&m[(long)d * 4 + h], x);
    }
}

__global__ void edge_exp1(const int* __restrict__ dst,
                          float* __restrict__ el, const float* __restrict__ m,
                          float* __restrict__ den) {
    int e = blockIdx.x * blockDim.x + threadIdx.x;
    if (e >= ET) return;
    int d = (e < NE) ? dst[e] : (e - NE);
    float4 mm = *(const float4*)(m + (long)d * 4);
    float4 ee = *(const float4*)(el + (long)e * 4);
    float ex0 = expf(ee.x - mm.x);
    float ex1 = expf(ee.y - mm.y);
    float ex2 = expf(ee.z - mm.z);
    float ex3 = expf(ee.w - mm.w);
    *(float4*)(el + (long)e * 4) = make_float4(ex0, ex1, ex2, ex3);
    atomicAdd(&den[(long)d * 4 + 0], ex0);
    atomicAdd(&den[(long)d * 4 + 1], ex1);
    atomicAdd(&den[(long)d * 4 + 2], ex2);
    atomicAdd(&den[(long)d * 4 + 3], ex3);
}

// ------------- aggregate layer 1: wave per edge, 128 feats -------------
__global__ __launch_bounds__(256) void agg1(const int* __restrict__ src, const int* __restrict__ dst,
                  const float* __restrict__ ex, const float* __restrict__ den,
                  const float* __restrict__ H, float* __restrict__ O) {
    long gt = (long)blockIdx.x * blockDim.x + threadIdx.x;
    long wid = gt >> 6;
    int lane = threadIdx.x & 63;
    if (wid >= ET) return;
    int s = (wid < NE) ? src[wid] : (int)(wid - NE);
    int d = (wid < NE) ? dst[wid] : (int)(wid - NE);
    #pragma unroll
    for (int j = 0; j < 2; ++j) {
        int hc = lane + j * 64;
        int h = hc >> 5;
        float alpha = ex[wid * 4 + h] / (den[(long)d * 4 + h] + 1e-9f);
        atomicAdd(&O[(long)d * F1 + hc], alpha * H[(long)s * F1 + hc]);
    }
}

// ------------- bias + ELU in place: out1 -> h1 -------------
__global__ void elu1_kernel(float* __restrict__ O, const float* __restrict__ b) {
    long i = (long)blockIdx.x * blockDim.x + threadIdx.x;
    if (i >= (long)NN * F1) return;
    float v = O[i] + b[i & (F1 - 1)];
    O[i] = (v > 0.f) ? v : expm1f(v);
}

// ------------- GEMM2: [NN,128] x [128,40] -> z [NN,40] -------------
__global__ __launch_bounds__(256) void gemm2_kernel(const float* __restrict__ H1,
        const float* __restrict__ W2, float* __restrict__ Z) {
    __shared__ float Ws[F1 * NC];
    for (int i = threadIdx.x; i < F1 * NC; i += 256) Ws[i] = W2[i];
    __syncthreads();
    long idx = (long)blockIdx.x * blockDim.x + threadIdx.x;
    if (idx >= (long)NN * NC) return;
    int n = (int)(idx / NC), c = (int)(idx % NC);
    const float* hp = H1 + (long)n * F1;
    float s = 0.f;
    #pragma unroll 8
    for (int k = 0; k < F1; ++k) s += hp[k] * Ws[k * NC + c];
    Z[idx] = s;
}

// ------------- per-node scores layer 2 -------------
__global__ void nscore2_kernel(const float* __restrict__ Z,
                               const float* __restrict__ a_src,
                               const float* __restrict__ a_dst,
                               float* __restrict__ ssrc, float* __restrict__ sdst) {
    int n = blockIdx.x * blockDim.x + threadIdx.x;
    if (n >= NN) return;
    const float* zp = Z + (long)n * NC;
    float s1 = 0.f, s2 = 0.f;
    #pragma unroll
    for (int c = 0; c < NC; ++c) {
        float v = zp[c];
        s1 += v * a_src[c];
        s2 += v * a_dst[c];
    }
    ssrc[n] = s1;
    sdst[n] = s2;
}

__global__ void edge_max2(const int* __restrict__ src, const int* __restrict__ dst,
                          const float* __restrict__ ssrc, const float* __restrict__ sdst,
                          float* __restrict__ el, float* __restrict__ m) {
    int e = blockIdx.x * blockDim.x + threadIdx.x;
    if (e >= ET) return;
    int s = (e < NE) ? src[e] : (e - NE);
    int d = (e < NE) ? dst[e] : (e - NE);
    float x = ssrc[s] + sdst[d];
    x = (x > 0.f) ? x : NEG * x;
    el[e] = x;
    atomicMaxF(&m[d], x);
}

__global__ void edge_exp2(const int* __restrict__ dst,
                          float* __restrict__ el, const float* __restrict__ m,
                          float* __restrict__ den) {
    int e = blockIdx.x * blockDim.x + threadIdx.x;
    if (e >= ET) return;
    int d = (e < NE) ? dst[e] : (e - NE);
    float ex = expf(el[e] - m[d]);
    el[e] = ex;
    atomicAdd(&den[d], ex);
}

// ------------- aggregate layer 2: wave per edge, 40 feats -------------
__global__ __launch_bounds__(256) void agg2(const int* __restrict__ src, const int* __restrict__ dst,
                  const float* __restrict__ ex, const float* __restrict__ den,
                  const float* __restrict__ Z, float* __restrict__ O) {
    long gt = (long)blockIdx.x * blockDim.x + threadIdx.x;
    long wid = gt >> 6;
    int lane = threadIdx.x & 63;
    if (wid >= ET) return;
    int s = (wid < NE) ? src[wid] : (int)(wid - NE);
    int d = (wid < NE) ? dst[wid] : (int)(wid - NE);
    if (lane < NC) {
        float alpha = ex[wid] / (den[d] + 1e-9f);
        atomicAdd(&O[(long)d * NC + lane], alpha * Z[(long)s * NC + lane]);
    }
}

// ------------- bias + row softmax -> out -------------
__global__ __launch_bounds__(256) void softmax_kernel(const float* __restrict__ O,
        const float* __restrict__ b, float* __restrict__ out) {
    long gt = (long)blockIdx.x * blockDim.x + threadIdx.x;
    long n = gt >> 6;
    int lane = threadIdx.x & 63;
    if (n >= NN) return;
    float v = (lane < NC) ? O[n * NC + lane] + b[lane] : -INFINITY;
    float mx = v;
    #pragma unroll
    for (int o = 32; o > 0; o >>= 1) mx = fmaxf(mx, __shfl_xor(mx, o));
    float e = (lane < NC) ? expf(v - mx) : 0.f;
    float sum = e;
    #pragma unroll
    for (int o = 32; o > 0; o >>= 1) sum += __shfl_xor(sum, o);
    if (lane < NC) out[n * NC + lane] = e / sum;
}

extern "C" void kernel_launch(void* const* d_in, const int* in_sizes, int n_in,
                              void* d_out, int out_size, void* d_ws, size_t ws_size,
                              hipStream_t stream) {
    const float* x      = (const float*)d_in[0];
    const int*   src    = (const int*)  d_in[1];
    const int*   dst    = (const int*)  d_in[2];
    const float* W1     = (const float*)d_in[3];
    const float* a_src1 = (const float*)d_in[4];
    const float* a_dst1 = (const float*)d_in[5];
    const float* b1     = (const float*)d_in[6];
    const float* W2     = (const float*)d_in[7];
    const float* a_src2 = (const float*)d_in[8];
    const float* a_dst2 = (const float*)d_in[9];
    const float* b2     = (const float*)d_in[10];
    float* out = (float*)d_out;

    // ws layout (floats); total 22,050,000 floats = 88.2 MB
    float* ws   = (float*)d_ws;
    float* hpre = ws;                   // 6,400,000
    float* s1s  = hpre + 6400000;       //   200,000
    float* s1d  = s1s + 200000;         //   200,000
    float* el1  = s1d + 200000;         // 3,400,000  (logits, then exp in place)
    float* z2   = el1 + 3400000;        // 2,000,000
    float* s2s  = z2 + 2000000;         //    50,000
    float* s2d  = s2s + 50000;          //    50,000
    float* el2  = s2d + 50000;          //   850,000
    float* m1   = el2 + 850000;         //   200,000  -inf fill start
    float* m2   = m1 + 200000;          //    50,000
    float* d1   = m2 + 50000;           //   200,000  zero fill start
    float* out1 = d1 + 200000;          // 6,400,000
    float* dd2  = out1 + 6400000;       //    50,000
    float* out2 = dd2 + 50000;          // 2,000,000

    // init: m1,m2 = -inf (250k), d1,out1,dd2,out2 = 0 (8.65M)
    fill_kernel<<<(250000 + 255) / 256, 256, 0, stream>>>(m1, 250000L, -INFINITY);
    fill_kernel<<<(8650000 + 255) / 256, 256, 0, stream>>>(d1, 8650000L, 0.f);

    gemm1_kernel<<<(NN + 63) / 64, 256, 0, stream>>>(x, W1, hpre);
    nscore1_kernel<<<(NN * 4 + 255) / 256, 256, 0, stream>>>(hpre, a_src1, a_dst1, s1s, s1d);
    edge_max1<<<(ET + 255) / 256, 256, 0, stream>>>(src, dst, s1s, s1d, el1, m1);
    edge_exp1<<<(ET + 255) / 256, 256, 0, stream>>>(dst, el1, m1, d1);
    agg1<<<(int)(((long)ET * 64 + 255) / 256), 256, 0, stream>>>(src, dst, el1, d1, hpre, out1);
    elu1_kernel<<<(int)(((long)NN * F1 + 255) / 256), 256, 0, stream>>>(out1, b1);

    gemm2_kernel<<<(int)(((long)NN * NC + 255) / 256), 256, 0, stream>>>(out1, W2, z2);
    nscore2_kernel<<<(NN + 255) / 256, 256, 0, stream>>>(z2, a_src2, a_dst2, s2s, s2d);
    edge_max2<<<(ET + 255) / 256, 256, 0, stream>>>(src, dst, s2s, s2d, el2, m2);
    edge_exp2<<<(ET + 255) / 256, 256, 0, stream>>>(dst, el2, m2, dd2);
    agg2<<<(int)(((long)ET * 64 + 255) / 256), 256, 0, stream>>>(src, dst, el2, dd2, z2, out2);
    softmax_kernel<<<(int)(((long)NN * 64 + 255) / 256), 256, 0, stream>>>(out2, b2, out);
}

// Round 2
// 716.194 us; speedup vs baseline: 1.7458x; 1.7458x over previous
//
#include <hip/hip_runtime.h>
#include <math.h>

// GAT 2-layer, MI355X. All f32. Node-centric CSR aggregation (no global atomics
// except tiny CSR-build counters).
#define NN 50000
#define NE 800000
#define ET 850000          // NE + NN self loops
#define DIN 512
#define F1 128             // HEADS*HIDDEN
#define NC 40
#define NEG 0.2f

// ---------------- CSR build ----------------
__global__ void zero_int_kernel(int* __restrict__ p, int n) {
    int i = blockIdx.x * blockDim.x + threadIdx.x;
    if (i < n) p[i] = 0;
}

__global__ void hist_kernel(const int* __restrict__ dst, int* __restrict__ deg) {
    int e = blockIdx.x * blockDim.x + threadIdx.x;
    if (e >= ET) return;
    int d = (e < NE) ? dst[e] : (e - NE);
    atomicAdd(&deg[d], 1);
}

__global__ __launch_bounds__(1024) void scan_kernel(const int* __restrict__ deg,
        int* __restrict__ off, int* __restrict__ cur) {
    __shared__ int part[1024];
    const int t = threadIdx.x;
    const int CH = (NN + 1023) / 1024;   // 49
    int lo = t * CH, hi = lo + CH;
    if (hi > NN) hi = NN;
    int s = 0;
    for (int i = lo; i < hi; ++i) s += deg[i];
    part[t] = s;
    __syncthreads();
    // inclusive scan over 1024 partials
    for (int o = 1; o < 1024; o <<= 1) {
        int v = (t >= o) ? part[t - o] : 0;
        __syncthreads();
        part[t] += v;
        __syncthreads();
    }
    int run = (t == 0) ? 0 : part[t - 1];
    for (int i = lo; i < hi; ++i) {
        off[i] = run;
        cur[i] = run;
        run += deg[i];
    }
    if (t == 0) off[NN] = ET;
}

__global__ void scatter_kernel(const int* __restrict__ src, const int* __restrict__ dst,
        int* __restrict__ cur, int* __restrict__ ssorted) {
    int e = blockIdx.x * blockDim.x + threadIdx.x;
    if (e >= ET) return;
    int s = (e < NE) ? src[e] : (e - NE);
    int d = (e < NE) ? dst[e] : (e - NE);
    int pos = atomicAdd(&cur[d], 1);
    ssorted[pos] = s;
}

// ---------------- GEMM1: [NN,512] x [512,128] -> hpre [NN,128] ----------------
__global__ __launch_bounds__(256) void gemm1_kernel(const float* __restrict__ X,
        const float* __restrict__ W, float* __restrict__ H) {
    __shared__ float As[64 * 33];
    __shared__ float Bs[32 * F1];
    const int tid  = threadIdx.x;
    const int row0 = blockIdx.x * 64;
    const int trow = tid >> 4;   // 0..15
    const int tcol = tid & 15;   // 0..15
    float acc[4][8];
    #pragma unroll
    for (int r = 0; r < 4; ++r)
        #pragma unroll
        for (int c = 0; c < 8; ++c) acc[r][c] = 0.f;

    for (int k0 = 0; k0 < DIN; k0 += 32) {
        #pragma unroll
        for (int j = 0; j < 2; ++j) {
            int idx = tid + j * 256;          // 512 float4 of A tile
            int r = idx >> 3, c = (idx & 7) << 2;
            int gr = row0 + r;
            float4 v = make_float4(0.f, 0.f, 0.f, 0.f);
            if (gr < NN) v = *(const float4*)(X + (long)gr * DIN + k0 + c);
            As[r * 33 + c + 0] = v.x;
            As[r * 33 + c + 1] = v.y;
            As[r * 33 + c + 2] = v.z;
            As[r * 33 + c + 3] = v.w;
        }
        #pragma unroll
        for (int j = 0; j < 4; ++j) {
            int idx = tid + j * 256;          // 1024 float4 of B tile
            int r = idx >> 5, c = (idx & 31) << 2;
            *(float4*)(&Bs[r * F1 + c]) = *(const float4*)(W + (k0 + r) * F1 + c);
        }
        __syncthreads();
        #pragma unroll
        for (int k = 0; k < 32; ++k) {
            float aa[4];
            #pragma unroll
            for (int r = 0; r < 4; ++r) aa[r] = As[(trow * 4 + r) * 33 + k];
            float4 b0 = *(const float4*)(&Bs[k * F1 + tcol * 8]);
            float4 b1 = *(const float4*)(&Bs[k * F1 + tcol * 8 + 4]);
            float bb[8] = {b0.x, b0.y, b0.z, b0.w, b1.x, b1.y, b1.z, b1.w};
            #pragma unroll
            for (int r = 0; r < 4; ++r)
                #pragma unroll
                for (int c = 0; c < 8; ++c)
                    acc[r][c] += aa[r] * bb[c];
        }
        __syncthreads();
    }
    #pragma unroll
    for (int r = 0; r < 4; ++r) {
        int gr = row0 + trow * 4 + r;
        if (gr < NN) {
            float4 o0 = make_float4(acc[r][0], acc[r][1], acc[r][2], acc[r][3]);
            float4 o1 = make_float4(acc[r][4], acc[r][5], acc[r][6], acc[r][7]);
            *(float4*)(H + (long)gr * F1 + tcol * 8)     = o0;
            *(float4*)(H + (long)gr * F1 + tcol * 8 + 4) = o1;
        }
    }
}

// ------------- per-node attention scores, layer 1: [NN,4] each -------------
__global__ void nscore1_kernel(const float* __restrict__ H,
                               const float* __restrict__ a_src,
                               const float* __restrict__ a_dst,
                               float* __restrict__ ssrc, float* __restrict__ sdst) {
    int i = blockIdx.x * blockDim.x + threadIdx.x;   // n*4 + h
    if (i >= NN * 4) return;
    int n = i >> 2, h = i & 3;
    const float* hp = H + (long)n * F1 + h * 32;
    float s1 = 0.f, s2 = 0.f;
    #pragma unroll
    for (int c = 0; c < 32; ++c) {
        float v = hp[c];
        s1 += v * a_src[h * 32 + c];
        s2 += v * a_dst[h * 32 + c];
    }
    ssrc[i] = s1;
    sdst[i] = s2;
}

// ------------- fused layer-1 softmax + aggregate + bias + ELU -------------
// wave per dst node; lanes = features (2 per lane).
__global__ __launch_bounds__(256) void fusedagg1_kernel(
        const int* __restrict__ off, const int* __restrict__ ssorted,
        const float* __restrict__ ssrc, const float* __restrict__ sdst,
        const float* __restrict__ H, const float* __restrict__ b,
        float* __restrict__ O) {
    int n = blockIdx.x * 4 + (threadIdx.x >> 6);
    if (n >= NN) return;
    const int lane = threadIdx.x & 63;
    const int base = off[n];
    const int deg  = off[n + 1] - base;
    const float4 vd = *(const float4*)(sdst + (long)n * 4);

    // pass 1: online softmax max+sum per head (lane-local, then wave merge)
    float m0 = -1e30f, m1 = -1e30f, m2 = -1e30f, m3 = -1e30f;
    float t0 = 0.f, t1 = 0.f, t2 = 0.f, t3 = 0.f;
    for (int k = lane; k < deg; k += 64) {
        int s = ssorted[base + k];
        float4 vs = *(const float4*)(ssrc + (long)s * 4);
        float x0 = vs.x + vd.x; x0 = (x0 > 0.f) ? x0 : NEG * x0;
        float x1 = vs.y + vd.y; x1 = (x1 > 0.f) ? x1 : NEG * x1;
        float x2 = vs.z + vd.z; x2 = (x2 > 0.f) ? x2 : NEG * x2;
        float x3 = vs.w + vd.w; x3 = (x3 > 0.f) ? x3 : NEG * x3;
        if (x0 > m0) { t0 = t0 * __expf(m0 - x0) + 1.f; m0 = x0; } else t0 += __expf(x0 - m0);
        if (x1 > m1) { t1 = t1 * __expf(m1 - x1) + 1.f; m1 = x1; } else t1 += __expf(x1 - m1);
        if (x2 > m2) { t2 = t2 * __expf(m2 - x2) + 1.f; m2 = x2; } else t2 += __expf(x2 - m2);
        if (x3 > m3) { t3 = t3 * __expf(m3 - x3) + 1.f; m3 = x3; } else t3 += __expf(x3 - m3);
    }
    #define MERGE(m, t)                                                     \
    for (int o = 1; o < 64; o <<= 1) {                                      \
        float mm = __shfl_xor(m, o), tt = __shfl_xor(t, o);                 \
        float mn = fmaxf(m, mm);                                            \
        t = t * __expf(m - mn) + tt * __expf(mm - mn);                      \
        m = mn;                                                             \
    }
    MERGE(m0, t0) MERGE(m1, t1) MERGE(m2, t2) MERGE(m3, t3)
    #undef MERGE
    const float i0 = 1.f / (t0 + 1e-9f);
    const float i1 = 1.f / (t1 + 1e-9f);
    const float i2 = 1.f / (t2 + 1e-9f);
    const float i3 = 1.f / (t3 + 1e-9f);

    // pass 2: serial edge loop, lanes = features. feature lane -> head lane>>5;
    // feature lane+64 -> head 2+(lane>>5).
    const int hA = lane >> 5;         // 0 or 1
    const float sdA = hA ? vd.y : vd.x;
    const float sdB = hA ? vd.w : vd.z;
    const float mA = hA ? m1 : m0, iA = hA ? i1 : i0;
    const float mB = hA ? m3 : m2, iB = hA ? i3 : i2;
    float acc0 = 0.f, acc1 = 0.f;
    for (int k = 0; k < deg; ++k) {
        int s = ssorted[base + k];
        float4 vs = *(const float4*)(ssrc + (long)s * 4);
        float xA = (hA ? vs.y : vs.x) + sdA; xA = (xA > 0.f) ? xA : NEG * xA;
        float xB = (hA ? vs.w : vs.z) + sdB; xB = (xB > 0.f) ? xB : NEG * xB;
        float aA = __expf(xA - mA) * iA;
        float aB = __expf(xB - mB) * iB;
        const float* hp = H + (long)s * F1;
        acc0 += aA * hp[lane];
        acc1 += aB * hp[64 + lane];
    }
    float v0 = acc0 + b[lane];
    float v1 = acc1 + b[64 + lane];
    v0 = (v0 > 0.f) ? v0 : expm1f(v0);
    v1 = (v1 > 0.f) ? v1 : expm1f(v1);
    O[(long)n * F1 + lane]      = v0;
    O[(long)n * F1 + 64 + lane] = v1;
}

// ------------- GEMM2: [NN,128] x [128,40] -> z [NN,40] -------------
__global__ __launch_bounds__(256) void gemm2_kernel(const float* __restrict__ H1,
        const float* __restrict__ W2, float* __restrict__ Z) {
    __shared__ float Ws[F1 * NC];
    for (int i = threadIdx.x; i < F1 * NC; i += 256) Ws[i] = W2[i];
    __syncthreads();
    long idx = (long)blockIdx.x * blockDim.x + threadIdx.x;
    if (idx >= (long)NN * NC) return;
    int n = (int)(idx / NC), c = (int)(idx % NC);
    const float* hp = H1 + (long)n * F1;
    float s = 0.f;
    #pragma unroll 8
    for (int k = 0; k < F1; ++k) s += hp[k] * Ws[k * NC + c];
    Z[idx] = s;
}

// ------------- per-node scores layer 2 -------------
__global__ void nscore2_kernel(const float* __restrict__ Z,
                               const float* __restrict__ a_src,
                               const float* __restrict__ a_dst,
                               float* __restrict__ ssrc, float* __restrict__ sdst) {
    int n = blockIdx.x * blockDim.x + threadIdx.x;
    if (n >= NN) return;
    const float* zp = Z + (long)n * NC;
    float s1 = 0.f, s2 = 0.f;
    #pragma unroll
    for (int c = 0; c < NC; ++c) {
        float v = zp[c];
        s1 += v * a_src[c];
        s2 += v * a_dst[c];
    }
    ssrc[n] = s1;
    sdst[n] = s2;
}

// ------------- fused layer-2 softmax + aggregate + bias + row softmax -------------
__global__ __launch_bounds__(256) void fusedagg2_kernel(
        const int* __restrict__ off, const int* __restrict__ ssorted,
        const float* __restrict__ ssrc, const float* __restrict__ sdst,
        const float* __restrict__ Z, const float* __restrict__ b,
        float* __restrict__ out) {
    int n = blockIdx.x * 4 + (threadIdx.x >> 6);
    if (n >= NN) return;
    const int lane = threadIdx.x & 63;
    const int base = off[n];
    const int deg  = off[n + 1] - base;
    const float sdn = sdst[n];

    // pass 1: online max+sum
    float m = -1e30f, t = 0.f;
    for (int k = lane; k < deg; k += 64) {
        int s = ssorted[base + k];
        float x = ssrc[s] + sdn;
        x = (x > 0.f) ? x : NEG * x;
        if (x > m) { t = t * __expf(m - x) + 1.f; m = x; } else t += __expf(x - m);
    }
    for (int o = 1; o < 64; o <<= 1) {
        float mm = __shfl_xor(m, o), tt = __shfl_xor(t, o);
        float mn = fmaxf(m, mm);
        t = t * __expf(m - mn) + tt * __expf(mm - mn);
        m = mn;
    }
    const float inv = 1.f / (t + 1e-9f);

    // pass 2: serial edge loop, lanes 0..39 = classes
    float acc = 0.f;
    for (int k = 0; k < deg; ++k) {
        int s = ssorted[base + k];
        float x = ssrc[s] + sdn;
        x = (x > 0.f) ? x : NEG * x;
        float a = __expf(x - m) * inv;
        if (lane < NC) acc += a * Z[(long)s * NC + lane];
    }
    // bias + row softmax over 40 classes
    float v = (lane < NC) ? acc + b[lane] : -1e30f;
    float mx = v;
    #pragma unroll
    for (int o = 32; o > 0; o >>= 1) mx = fmaxf(mx, __shfl_xor(mx, o));
    float e = (lane < NC) ? __expf(v - mx) : 0.f;
    float sum = e;
    #pragma unroll
    for (int o = 32; o > 0; o >>= 1) sum += __shfl_xor(sum, o);
    if (lane < NC) out[(long)n * NC + lane] = e / sum;
}

extern "C" void kernel_launch(void* const* d_in, const int* in_sizes, int n_in,
                              void* d_out, int out_size, void* d_ws, size_t ws_size,
                              hipStream_t stream) {
    const float* x      = (const float*)d_in[0];
    const int*   src    = (const int*)  d_in[1];
    const int*   dst    = (const int*)  d_in[2];
    const float* W1     = (const float*)d_in[3];
    const float* a_src1 = (const float*)d_in[4];
    const float* a_dst1 = (const float*)d_in[5];
    const float* b1     = (const float*)d_in[6];
    const float* W2     = (const float*)d_in[7];
    const float* a_src2 = (const float*)d_in[8];
    const float* a_dst2 = (const float*)d_in[9];
    const float* b2     = (const float*)d_in[10];
    float* out = (float*)d_out;

    // ws layout: floats then ints. 15.3M floats + ~1.0M ints ≈ 65.2 MB.
    float* ws   = (float*)d_ws;
    float* hpre = ws;                   // 6,400,000
    float* s1s  = hpre + 6400000;       //   200,000
    float* s1d  = s1s + 200000;         //   200,000
    float* h1   = s1d + 200000;         // 6,400,000
    float* z2   = h1 + 6400000;         // 2,000,000
    float* s2s  = z2 + 2000000;         //    50,000
    float* s2d  = s2s + 50000;          //    50,000
    int*   deg     = (int*)(s2d + 50000);   //  50,000
    int*   off     = deg + 50000;           //  50,001
    int*   cur     = off + 50001;           //  50,000
    int*   ssorted = cur + 50000;           // 850,000

    // CSR build (by dst)
    zero_int_kernel<<<(50000 + 255) / 256, 256, 0, stream>>>(deg, 50000);
    hist_kernel<<<(ET + 255) / 256, 256, 0, stream>>>(dst, deg);
    scan_kernel<<<1, 1024, 0, stream>>>(deg, off, cur);
    scatter_kernel<<<(ET + 255) / 256, 256, 0, stream>>>(src, dst, cur, ssorted);

    // layer 1
    gemm1_kernel<<<(NN + 63) / 64, 256, 0, stream>>>(x, W1, hpre);
    nscore1_kernel<<<(NN * 4 + 255) / 256, 256, 0, stream>>>(hpre, a_src1, a_dst1, s1s, s1d);
    fusedagg1_kernel<<<(NN + 3) / 4, 256, 0, stream>>>(off, ssorted, s1s, s1d, hpre, b1, h1);

    // layer 2
    gemm2_kernel<<<(int)(((long)NN * NC + 255) / 256), 256, 0, stream>>>(h1, W2, z2);
    nscore2_kernel<<<(NN + 255) / 256, 256, 0, stream>>>(z2, a_src2, a_dst2, s2s, s2d);
    fusedagg2_kernel<<<(NN + 3) / 4, 256, 0, stream>>>(off, ssorted, s2s, s2d, z2, b2, out);
}

// Round 3
// 617.422 us; speedup vs baseline: 2.0251x; 1.1600x over previous
//
#include <hip/hip_runtime.h>
#include <hip/hip_bf16.h>
#include <math.h>

// GAT 2-layer, MI355X. CSR aggregation + MFMA GEMMs (3-term bf16 split ~ f32 accuracy).
#define NN 50000
#define NE 800000
#define ET 850000          // NE + NN self loops
#define DIN 512
#define F1 128             // HEADS*HIDDEN
#define NC 40
#define NEG 0.2f

typedef __attribute__((ext_vector_type(8))) short s16x8;
typedef __attribute__((ext_vector_type(4))) float f32x4;

__device__ inline unsigned short bfh(float f) {
    __hip_bfloat16 h = __float2bfloat16(f);
    return __builtin_bit_cast(unsigned short, h);
}
__device__ inline float bff(unsigned short u) {
    unsigned int x = (unsigned int)u << 16;
    return __builtin_bit_cast(float, x);
}

// split 8 f32 -> hi/lo bf16 fragments
__device__ inline void split8(f32x4 v0, f32x4 v1, s16x8* hi, s16x8* lo) {
    float f[8] = {v0.x, v0.y, v0.z, v0.w, v1.x, v1.y, v1.z, v1.w};
    #pragma unroll
    for (int j = 0; j < 8; ++j) {
        unsigned short h = bfh(f[j]);
        (*hi)[j] = (short)h;
        (*lo)[j] = (short)bfh(f[j] - bff(h));
    }
}

__device__ inline void gl16(const void* g, void* l) {
    __builtin_amdgcn_global_load_lds((const __attribute__((address_space(1))) unsigned int*)g,
                                     (__attribute__((address_space(3))) unsigned int*)l, 16, 0, 0);
}

// ---------------- CSR build ----------------
__global__ void zero_int_kernel(int* __restrict__ p, int n) {
    int i = blockIdx.x * blockDim.x + threadIdx.x;
    if (i < n) p[i] = 0;
}

__global__ void hist_kernel(const int* __restrict__ dst, int* __restrict__ deg) {
    int e = blockIdx.x * blockDim.x + threadIdx.x;
    if (e >= ET) return;
    int d = (e < NE) ? dst[e] : (e - NE);
    atomicAdd(&deg[d], 1);
}

__global__ __launch_bounds__(1024) void scan_kernel(const int* __restrict__ deg,
        int* __restrict__ off, int* __restrict__ cur) {
    __shared__ int part[1024];
    const int t = threadIdx.x;
    const int CH = (NN + 1023) / 1024;   // 49
    int lo = t * CH, hi = lo + CH;
    if (hi > NN) hi = NN;
    int s = 0;
    for (int i = lo; i < hi; ++i) s += deg[i];
    part[t] = s;
    __syncthreads();
    for (int o = 1; o < 1024; o <<= 1) {
        int v = (t >= o) ? part[t - o] : 0;
        __syncthreads();
        part[t] += v;
        __syncthreads();
    }
    int run = (t == 0) ? 0 : part[t - 1];
    for (int i = lo; i < hi; ++i) {
        off[i] = run;
        cur[i] = run;
        run += deg[i];
    }
    if (t == 0) off[NN] = ET;
}

__global__ void scatter_kernel(const int* __restrict__ src, const int* __restrict__ dst,
        int* __restrict__ cur, int* __restrict__ ssorted) {
    int e = blockIdx.x * blockDim.x + threadIdx.x;
    if (e >= ET) return;
    int s = (e < NE) ? src[e] : (e - NE);
    int d = (e < NE) ? dst[e] : (e - NE);
    int pos = atomicAdd(&cur[d], 1);
    ssorted[pos] = s;
}

// ---------------- weight split kernels ----------------
// W1 [512][128] f32 -> WhT/WlT [128][512] bf16 (transposed)
__global__ void wsplit1_kernel(const float* __restrict__ W,
        unsigned short* __restrict__ WhT, unsigned short* __restrict__ WlT) {
    int i = blockIdx.x * blockDim.x + threadIdx.x;
    if (i >= DIN * F1) return;
    int k = i >> 7, c = i & 127;
    float w = W[i];
    unsigned short h = bfh(w);
    unsigned short l = bfh(w - bff(h));
    WhT[c * DIN + k] = h;
    WlT[c * DIN + k] = l;
}

// W2 [128][40] f32 -> padded transposed [48][128] bf16
__global__ void wsplit2_kernel(const float* __restrict__ W,
        unsigned short* __restrict__ WhT, unsigned short* __restrict__ WlT) {
    int i = blockIdx.x * blockDim.x + threadIdx.x;
    if (i >= 48 * 128) return;
    int c = i >> 7, k = i & 127;
    float w = (c < NC) ? W[k * NC + c] : 0.f;
    unsigned short h = bfh(w);
    unsigned short l = bfh(w - bff(h));
    WhT[c * 128 + k] = h;
    WlT[c * 128 + k] = l;
}

// ---------------- GEMM1 MFMA: [NN,512] x [512,128] -> hpre, + fused scores ----------------
// block 256 = 4 waves (wm 0..1, wn 0..1), BM=64, BN=128, BK=64, wave tile 32x64.
__global__ __launch_bounds__(256) void gemm1_mfma(const float* __restrict__ X,
        const unsigned short* __restrict__ BhT, const unsigned short* __restrict__ BlT,
        const float* __restrict__ a_src, const float* __restrict__ a_dst,
        float* __restrict__ H, float* __restrict__ s1s, float* __restrict__ s1d) {
    __shared__ char lds[49152];               // A 16K | Bh 16K | Bl 16K
    char* ldsA  = lds;
    char* ldsBh = lds + 16384;
    char* ldsBl = lds + 32768;
    const int tid = threadIdx.x;
    const int wid = tid >> 6, lane = tid & 63;
    const int wm = wid >> 1, wn = wid & 1;
    const int l15 = lane & 15, lg = lane >> 4;
    const int row0 = blockIdx.x * 64;

    f32x4 acc[2][4];
    #pragma unroll
    for (int mi = 0; mi < 2; ++mi)
        #pragma unroll
        for (int ni = 0; ni < 4; ++ni) acc[mi][ni] = (f32x4)(0.f);

    for (int k0 = 0; k0 < DIN; k0 += 64) {
        // stage: A 1024 chunks, Bh 1024, Bl 1024 (16B each); 4 per thread per region
        #pragma unroll
        for (int p = 0; p < 4; ++p) {
            int q = p * 256 + tid;
            int dstoff = (p * 256 + wid * 64) << 4;
            {   // A [64][64] f32, swizzled source
                int row = q >> 4;
                int w = (q & 15) << 4;
                int sw = (row & 7) << 4;
                int gr = row0 + row; if (gr > NN - 1) gr = NN - 1;
                gl16((const char*)(X + (long)gr * DIN + k0) + (w ^ sw), ldsA + dstoff);
            }
            {   // Bh/Bl [128][64] bf16, swizzled source
                int rr = q >> 3;
                int w = (q & 7) << 4;
                int sw = (rr & 7) << 4;
                long sb = (long)rr * (DIN * 2) + k0 * 2 + (w ^ sw);
                gl16((const char*)BhT + sb, ldsBh + dstoff);
                gl16((const char*)BlT + sb, ldsBl + dstoff);
            }
        }
        __syncthreads();
        #pragma unroll
        for (int ks = 0; ks < 2; ++ks) {
            s16x8 ah[2], al[2], bh[4], bl[4];
            #pragma unroll
            for (int mi = 0; mi < 2; ++mi) {
                int row = wm * 32 + mi * 16 + l15;
                int sw = (row & 7) << 4;
                int kb = (ks * 32 + lg * 8) * 4;
                f32x4 v0 = *(const f32x4*)(ldsA + row * 256 + ((kb)      ^ sw));
                f32x4 v1 = *(const f32x4*)(ldsA + row * 256 + ((kb + 16) ^ sw));
                split8(v0, v1, &ah[mi], &al[mi]);
            }
            #pragma unroll
            for (int ni = 0; ni < 4; ++ni) {
                int col = wn * 64 + ni * 16 + l15;
                int sw = (col & 7) << 4;
                int kb = (ks * 32 + lg * 8) * 2;
                bh[ni] = *(const s16x8*)(ldsBh + col * 128 + (kb ^ sw));
                bl[ni] = *(const s16x8*)(ldsBl + col * 128 + (kb ^ sw));
            }
            #pragma unroll
            for (int mi = 0; mi < 2; ++mi)
                #pragma unroll
                for (int ni = 0; ni < 4; ++ni) {
                    acc[mi][ni] = __builtin_amdgcn_mfma_f32_16x16x32_bf16(ah[mi], bh[ni], acc[mi][ni], 0, 0, 0);
                    acc[mi][ni] = __builtin_amdgcn_mfma_f32_16x16x32_bf16(ah[mi], bl[ni], acc[mi][ni], 0, 0, 0);
                    acc[mi][ni] = __builtin_amdgcn_mfma_f32_16x16x32_bf16(al[mi], bh[ni], acc[mi][ni], 0, 0, 0);
                }
        }
        __syncthreads();
    }

    // epilogue: store H (C/D layout: col=lane&15, row=(lane>>4)*4+reg)
    #pragma unroll
    for (int mi = 0; mi < 2; ++mi)
        #pragma unroll
        for (int ni = 0; ni < 4; ++ni) {
            int col = wn * 64 + ni * 16 + l15;
            #pragma unroll
            for (int r = 0; r < 4; ++r) {
                int grow = row0 + wm * 32 + mi * 16 + lg * 4 + r;
                if (grow < NN) H[(long)grow * F1 + col] = acc[mi][ni][r];
            }
        }
    // fused per-node scores: head = col>>5 = 2*wn + (ni>>1)
    float av[4], bv[4];
    #pragma unroll
    for (int ni = 0; ni < 4; ++ni) {
        int col = wn * 64 + ni * 16 + l15;
        av[ni] = a_src[col];
        bv[ni] = a_dst[col];
    }
    #pragma unroll
    for (int mi = 0; mi < 2; ++mi)
        #pragma unroll
        for (int hl = 0; hl < 2; ++hl) {
            #pragma unroll
            for (int r = 0; r < 4; ++r) {
                float t1 = acc[mi][2 * hl][r] * av[2 * hl] + acc[mi][2 * hl + 1][r] * av[2 * hl + 1];
                float t2 = acc[mi][2 * hl][r] * bv[2 * hl] + acc[mi][2 * hl + 1][r] * bv[2 * hl + 1];
                #pragma unroll
                for (int o = 1; o < 16; o <<= 1) {
                    t1 += __shfl_xor(t1, o);
                    t2 += __shfl_xor(t2, o);
                }
                int grow = row0 + wm * 32 + mi * 16 + lg * 4 + r;
                if (l15 == 0 && grow < NN) {
                    int head = 2 * wn + hl;
                    s1s[grow * 4 + head] = t1;
                    s1d[grow * 4 + head] = t2;
                }
            }
        }
}

// ---------------- GEMM2 MFMA: [NN,128] x [128,40->48] -> Z, + fused scores ----------------
// block 256 = 4 waves (wm = wid), BM=64, BN=48, K=128 single stage. wave tile 16x48.
__global__ __launch_bounds__(256) void gemm2_mfma(const float* __restrict__ H1,
        const unsigned short* __restrict__ B2h, const unsigned short* __restrict__ B2l,
        const float* __restrict__ a_src, const float* __restrict__ a_dst,
        float* __restrict__ Z, float* __restrict__ s2s, float* __restrict__ s2d) {
    __shared__ char lds[57344];               // A 32K | Bh 12K | Bl 12K
    char* ldsA  = lds;
    char* ldsBh = lds + 32768;
    char* ldsBl = lds + 45056;
    const int tid = threadIdx.x;
    const int wid = tid >> 6, lane = tid & 63;
    const int l15 = lane & 15, lg = lane >> 4;
    const int row0 = blockIdx.x * 64;

    // stage A [64][128] f32: 2048 chunks
    #pragma unroll
    for (int p = 0; p < 8; ++p) {
        int q = p * 256 + tid;
        int row = q >> 5;
        int w = (q & 31) << 4;
        int sw = (row & 7) << 4;
        int gr = row0 + row; if (gr > NN - 1) gr = NN - 1;
        gl16((const char*)(H1 + (long)gr * F1) + (w ^ sw), ldsA + ((p * 256 + wid * 64) << 4));
    }
    // stage B [48][128] bf16: 768 chunks each
    #pragma unroll
    for (int p = 0; p < 3; ++p) {
        int q = p * 256 + tid;
        int rr = q >> 4;
        int w = (q & 15) << 4;
        int sw = (rr & 7) << 4;
        int dstoff = (p * 256 + wid * 64) << 4;
        gl16((const char*)B2h + rr * 256 + (w ^ sw), ldsBh + dstoff);
        gl16((const char*)B2l + rr * 256 + (w ^ sw), ldsBl + dstoff);
    }
    __syncthreads();

    f32x4 acc[3];
    #pragma unroll
    for (int ni = 0; ni < 3; ++ni) acc[ni] = (f32x4)(0.f);

    #pragma unroll
    for (int ks = 0; ks < 4; ++ks) {
        int row = wid * 16 + l15;
        int sw = (row & 7) << 4;
        int kb = (ks * 32 + lg * 8) * 4;
        f32x4 v0 = *(const f32x4*)(ldsA + row * 512 + ((kb)      ^ sw));
        f32x4 v1 = *(const f32x4*)(ldsA + row * 512 + ((kb + 16) ^ sw));
        s16x8 ah, al;
        split8(v0, v1, &ah, &al);
        #pragma unroll
        for (int ni = 0; ni < 3; ++ni) {
            int cc = ni * 16 + l15;
            int swb = (cc & 7) << 4;
            int kb2 = (ks * 32 + lg * 8) * 2;
            s16x8 bh = *(const s16x8*)(ldsBh + cc * 256 + (kb2 ^ swb));
            s16x8 bl = *(const s16x8*)(ldsBl + cc * 256 + (kb2 ^ swb));
            acc[ni] = __builtin_amdgcn_mfma_f32_16x16x32_bf16(ah, bh, acc[ni], 0, 0, 0);
            acc[ni] = __builtin_amdgcn_mfma_f32_16x16x32_bf16(ah, bl, acc[ni], 0, 0, 0);
            acc[ni] = __builtin_amdgcn_mfma_f32_16x16x32_bf16(al, bh, acc[ni], 0, 0, 0);
        }
    }

    float av[3], bv[3];
    #pragma unroll
    for (int ni = 0; ni < 3; ++ni) {
        int cc = ni * 16 + l15;
        av[ni] = (cc < NC) ? a_src[cc] : 0.f;
        bv[ni] = (cc < NC) ? a_dst[cc] : 0.f;
    }
    #pragma unroll
    for (int r = 0; r < 4; ++r) {
        int grow = row0 + wid * 16 + lg * 4 + r;
        bool ok = grow < NN;
        float t1 = acc[0][r] * av[0] + acc[1][r] * av[1] + acc[2][r] * av[2];
        float t2 = acc[0][r] * bv[0] + acc[1][r] * bv[1] + acc[2][r] * bv[2];
        #pragma unroll
        for (int o = 1; o < 16; o <<= 1) {
            t1 += __shfl_xor(t1, o);
            t2 += __shfl_xor(t2, o);
        }
        #pragma unroll
        for (int ni = 0; ni < 3; ++ni) {
            int cc = ni * 16 + l15;
            if (ok && cc < NC) Z[(long)grow * NC + cc] = acc[ni][r];
        }
        if (ok && l15 == 0) { s2s[grow] = t1; s2d[grow] = t2; }
    }
}

// ------------- fused layer-1 softmax + aggregate + bias + ELU -------------
__global__ __launch_bounds__(256) void fusedagg1_kernel(
        const int* __restrict__ off, const int* __restrict__ ssorted,
        const float* __restrict__ ssrc, const float* __restrict__ sdst,
        const float* __restrict__ H, const float* __restrict__ b,
        float* __restrict__ O) {
    int n = blockIdx.x * 4 + (threadIdx.x >> 6);
    if (n >= NN) return;
    const int lane = threadIdx.x & 63;
    const int base = off[n];
    const int deg  = off[n + 1] - base;
    const float4 vd = *(const float4*)(sdst + (long)n * 4);

    float m0 = -1e30f, m1 = -1e30f, m2 = -1e30f, m3 = -1e30f;
    float t0 = 0.f, t1 = 0.f, t2 = 0.f, t3 = 0.f;
    for (int k = lane; k < deg; k += 64) {
        int s = ssorted[base + k];
        float4 vs = *(const float4*)(ssrc + (long)s * 4);
        float x0 = vs.x + vd.x; x0 = (x0 > 0.f) ? x0 : NEG * x0;
        float x1 = vs.y + vd.y; x1 = (x1 > 0.f) ? x1 : NEG * x1;
        float x2 = vs.z + vd.z; x2 = (x2 > 0.f) ? x2 : NEG * x2;
        float x3 = vs.w + vd.w; x3 = (x3 > 0.f) ? x3 : NEG * x3;
        if (x0 > m0) { t0 = t0 * __expf(m0 - x0) + 1.f; m0 = x0; } else t0 += __expf(x0 - m0);
        if (x1 > m1) { t1 = t1 * __expf(m1 - x1) + 1.f; m1 = x1; } else t1 += __expf(x1 - m1);
        if (x2 > m2) { t2 = t2 * __expf(m2 - x2) + 1.f; m2 = x2; } else t2 += __expf(x2 - m2);
        if (x3 > m3) { t3 = t3 * __expf(m3 - x3) + 1.f; m3 = x3; } else t3 += __expf(x3 - m3);
    }
    #define MERGE(m, t)                                                     \
    for (int o = 1; o < 64; o <<= 1) {                                      \
        float mm = __shfl_xor(m, o), tt = __shfl_xor(t, o);                 \
        float mn = fmaxf(m, mm);                                            \
        t = t * __expf(m - mn) + tt * __expf(mm - mn);                      \
        m = mn;                                                             \
    }
    MERGE(m0, t0) MERGE(m1, t1) MERGE(m2, t2) MERGE(m3, t3)
    #undef MERGE
    const float i0 = 1.f / (t0 + 1e-9f);
    const float i1 = 1.f / (t1 + 1e-9f);
    const float i2 = 1.f / (t2 + 1e-9f);
    const float i3 = 1.f / (t3 + 1e-9f);

    const int hA = lane >> 5;
    const float sdA = hA ? vd.y : vd.x;
    const float sdB = hA ? vd.w : vd.z;
    const float mA = hA ? m1 : m0, iA = hA ? i1 : i0;
    const float mB = hA ? m3 : m2, iB = hA ? i3 : i2;
    float acc0 = 0.f, acc1 = 0.f;
    for (int k = 0; k < deg; ++k) {
        int s = ssorted[base + k];
        float4 vs = *(const float4*)(ssrc + (long)s * 4);
        float xA = (hA ? vs.y : vs.x) + sdA; xA = (xA > 0.f) ? xA : NEG * xA;
        float xB = (hA ? vs.w : vs.z) + sdB; xB = (xB > 0.f) ? xB : NEG * xB;
        float aA = __expf(xA - mA) * iA;
        float aB = __expf(xB - mB) * iB;
        const float* hp = H + (long)s * F1;
        acc0 += aA * hp[lane];
        acc1 += aB * hp[64 + lane];
    }
    float v0 = acc0 + b[lane];
    float v1 = acc1 + b[64 + lane];
    v0 = (v0 > 0.f) ? v0 : expm1f(v0);
    v1 = (v1 > 0.f) ? v1 : expm1f(v1);
    O[(long)n * F1 + lane]      = v0;
    O[(long)n * F1 + 64 + lane] = v1;
}

// ------------- fused layer-2 softmax + aggregate + bias + row softmax -------------
__global__ __launch_bounds__(256) void fusedagg2_kernel(
        const int* __restrict__ off, const int* __restrict__ ssorted,
        const float* __restrict__ ssrc, const float* __restrict__ sdst,
        const float* __restrict__ Z, const float* __restrict__ b,
        float* __restrict__ out) {
    int n = blockIdx.x * 4 + (threadIdx.x >> 6);
    if (n >= NN) return;
    const int lane = threadIdx.x & 63;
    const int base = off[n];
    const int deg  = off[n + 1] - base;
    const float sdn = sdst[n];

    float m = -1e30f, t = 0.f;
    for (int k = lane; k < deg; k += 64) {
        int s = ssorted[base + k];
        float x = ssrc[s] + sdn;
        x = (x > 0.f) ? x : NEG * x;
        if (x > m) { t = t * __expf(m - x) + 1.f; m = x; } else t += __expf(x - m);
    }
    for (int o = 1; o < 64; o <<= 1) {
        float mm = __shfl_xor(m, o), tt = __shfl_xor(t, o);
        float mn = fmaxf(m, mm);
        t = t * __expf(m - mn) + tt * __expf(mm - mn);
        m = mn;
    }
    const float inv = 1.f / (t + 1e-9f);

    float acc = 0.f;
    for (int k = 0; k < deg; ++k) {
        int s = ssorted[base + k];
        float x = ssrc[s] + sdn;
        x = (x > 0.f) ? x : NEG * x;
        float a = __expf(x - m) * inv;
        if (lane < NC) acc += a * Z[(long)s * NC + lane];
    }
    float v = (lane < NC) ? acc + b[lane] : -1e30f;
    float mx = v;
    #pragma unroll
    for (int o = 32; o > 0; o >>= 1) mx = fmaxf(mx, __shfl_xor(mx, o));
    float e = (lane < NC) ? __expf(v - mx) : 0.f;
    float sum = e;
    #pragma unroll
    for (int o = 32; o > 0; o >>= 1) sum += __shfl_xor(sum, o);
    if (lane < NC) out[(long)n * NC + lane] = e / sum;
}

extern "C" void kernel_launch(void* const* d_in, const int* in_sizes, int n_in,
                              void* d_out, int out_size, void* d_ws, size_t ws_size,
                              hipStream_t stream) {
    const float* x      = (const float*)d_in[0];
    const int*   src    = (const int*)  d_in[1];
    const int*   dst    = (const int*)  d_in[2];
    const float* W1     = (const float*)d_in[3];
    const float* a_src1 = (const float*)d_in[4];
    const float* a_dst1 = (const float*)d_in[5];
    const float* b1     = (const float*)d_in[6];
    const float* W2     = (const float*)d_in[7];
    const float* a_src2 = (const float*)d_in[8];
    const float* a_dst2 = (const float*)d_in[9];
    const float* b2     = (const float*)d_in[10];
    float* out = (float*)d_out;

    // ws layout: 15.3M floats | 1,000,008 ints | 143,360 ushorts  (~65.5 MB)
    float* ws   = (float*)d_ws;
    float* hpre = ws;                   // 6,400,000
    float* s1s  = hpre + 6400000;       //   200,000
    float* s1d  = s1s + 200000;         //   200,000
    float* h1   = s1d + 200000;         // 6,400,000
    float* z2   = h1 + 6400000;         // 2,000,000
    float* s2s  = z2 + 2000000;         //    50,000
    float* s2d  = s2s + 50000;          //    50,000
    int*   deg     = (int*)(s2d + 50000);   //  50,000
    int*   off     = deg + 50000;           //  50,008 (padded for alignment)
    int*   cur     = off + 50008;           //  50,000
    int*   ssorted = cur + 50000;           // 850,000
    unsigned short* Wh1T = (unsigned short*)(ssorted + 850000); // 65,536
    unsigned short* Wl1T = Wh1T + 65536;                        // 65,536
    unsigned short* Wh2T = Wl1T + 65536;                        //  6,144
    unsigned short* Wl2T = Wh2T + 6144;                         //  6,144

    // CSR build (by dst)
    zero_int_kernel<<<(50000 + 255) / 256, 256, 0, stream>>>(deg, 50000);
    hist_kernel<<<(ET + 255) / 256, 256, 0, stream>>>(dst, deg);
    scan_kernel<<<1, 1024, 0, stream>>>(deg, off, cur);
    scatter_kernel<<<(ET + 255) / 256, 256, 0, stream>>>(src, dst, cur, ssorted);

    // weight splits
    wsplit1_kernel<<<(DIN * F1 + 255) / 256, 256, 0, stream>>>(W1, Wh1T, Wl1T);
    wsplit2_kernel<<<(48 * 128 + 255) / 256, 256, 0, stream>>>(W2, Wh2T, Wl2T);

    // layer 1
    gemm1_mfma<<<(NN + 63) / 64, 256, 0, stream>>>(x, Wh1T, Wl1T, a_src1, a_dst1, hpre, s1s, s1d);
    fusedagg1_kernel<<<(NN + 3) / 4, 256, 0, stream>>>(off, ssorted, s1s, s1d, hpre, b1, h1);

    // layer 2
    gemm2_mfma<<<(NN + 63) / 64, 256, 0, stream>>>(h1, Wh2T, Wl2T, a_src2, a_dst2, z2, s2s, s2d);
    fusedagg2_kernel<<<(NN + 3) / 4, 256, 0, stream>>>(off, ssorted, s2s, s2d, z2, b2, out);
}

// Round 4
// 526.995 us; speedup vs baseline: 2.3726x; 1.1716x over previous
//
#include <hip/hip_runtime.h>
#include <hip/hip_bf16.h>
#include <math.h>

// GAT 2-layer, MI355X. CSR aggregation (LDS-cached alphas) + MFMA GEMMs
// (3-term bf16 split ~ f32 accuracy, A-split hoisted to staging).
#define NN 50000
#define NE 800000
#define ET 850000          // NE + NN self loops
#define DIN 512
#define F1 128             // HEADS*HIDDEN
#define NC 40
#define NEG 0.2f
#define CAP 128            // per-node cached-edge cap (max degree ~50 stat.)

typedef __attribute__((ext_vector_type(8))) short s16x8;
typedef __attribute__((ext_vector_type(4))) float f32x4;

__device__ inline unsigned short bfh(float f) {
    __hip_bfloat16 h = __float2bfloat16(f);
    return __builtin_bit_cast(unsigned short, h);
}
__device__ inline float bff(unsigned short u) {
    unsigned int x = (unsigned int)u << 16;
    return __builtin_bit_cast(float, x);
}

__device__ inline void split8(f32x4 v0, f32x4 v1, s16x8* hi, s16x8* lo) {
    float f[8] = {v0.x, v0.y, v0.z, v0.w, v1.x, v1.y, v1.z, v1.w};
    #pragma unroll
    for (int j = 0; j < 8; ++j) {
        unsigned short h = bfh(f[j]);
        (*hi)[j] = (short)h;
        (*lo)[j] = (short)bfh(f[j] - bff(h));
    }
}

__device__ inline void gl16(const void* g, void* l) {
    __builtin_amdgcn_global_load_lds((const __attribute__((address_space(1))) unsigned int*)g,
                                     (__attribute__((address_space(3))) unsigned int*)l, 16, 0, 0);
}

// ---------------- CSR build ----------------
__global__ void zero_int_kernel(int* __restrict__ p, int n) {
    int i = blockIdx.x * blockDim.x + threadIdx.x;
    if (i < n) p[i] = 0;
}

__global__ void hist_kernel(const int* __restrict__ dst, int* __restrict__ deg) {
    int e = blockIdx.x * blockDim.x + threadIdx.x;
    if (e >= ET) return;
    int d = (e < NE) ? dst[e] : (e - NE);
    atomicAdd(&deg[d], 1);
}

__global__ __launch_bounds__(1024) void scan_kernel(const int* __restrict__ deg,
        int* __restrict__ off, int* __restrict__ cur) {
    __shared__ int part[1024];
    const int t = threadIdx.x;
    const int CH = (NN + 1023) / 1024;   // 49
    int lo = t * CH, hi = lo + CH;
    if (hi > NN) hi = NN;
    int s = 0;
    for (int i = lo; i < hi; ++i) s += deg[i];
    part[t] = s;
    __syncthreads();
    for (int o = 1; o < 1024; o <<= 1) {
        int v = (t >= o) ? part[t - o] : 0;
        __syncthreads();
        part[t] += v;
        __syncthreads();
    }
    int run = (t == 0) ? 0 : part[t - 1];
    for (int i = lo; i < hi; ++i) {
        off[i] = run;
        cur[i] = run;
        run += deg[i];
    }
    if (t == 0) off[NN] = ET;
}

__global__ void scatter_kernel(const int* __restrict__ src, const int* __restrict__ dst,
        int* __restrict__ cur, int* __restrict__ ssorted) {
    int e = blockIdx.x * blockDim.x + threadIdx.x;
    if (e >= ET) return;
    int s = (e < NE) ? src[e] : (e - NE);
    int d = (e < NE) ? dst[e] : (e - NE);
    int pos = atomicAdd(&cur[d], 1);
    ssorted[pos] = s;
}

// ---------------- weight split kernels ----------------
__global__ void wsplit1_kernel(const float* __restrict__ W,
        unsigned short* __restrict__ WhT, unsigned short* __restrict__ WlT) {
    int i = blockIdx.x * blockDim.x + threadIdx.x;
    if (i >= DIN * F1) return;
    int k = i >> 7, c = i & 127;
    float w = W[i];
    unsigned short h = bfh(w);
    unsigned short l = bfh(w - bff(h));
    WhT[c * DIN + k] = h;
    WlT[c * DIN + k] = l;
}

__global__ void wsplit2_kernel(const float* __restrict__ W,
        unsigned short* __restrict__ WhT, unsigned short* __restrict__ WlT) {
    int i = blockIdx.x * blockDim.x + threadIdx.x;
    if (i >= 48 * 128) return;
    int c = i >> 7, k = i & 127;
    float w = (c < NC) ? W[k * NC + c] : 0.f;
    unsigned short h = bfh(w);
    unsigned short l = bfh(w - bff(h));
    WhT[c * 128 + k] = h;
    WlT[c * 128 + k] = l;
}

// ---------------- GEMM1 MFMA: [NN,512] x [512,128] -> hpre, + fused scores ----------------
// block 256 = 4 waves (wm 0..1, wn 0..1), BM=64, BN=128, BK=64, wave tile 32x64.
// A reg-staged + pre-split to bf16 hi/lo in LDS; B via global_load_lds.
__global__ __launch_bounds__(256) void gemm1_mfma(const float* __restrict__ X,
        const unsigned short* __restrict__ BhT, const unsigned short* __restrict__ BlT,
        const float* __restrict__ a_src, const float* __restrict__ a_dst,
        float* __restrict__ H, float* __restrict__ s1s, float* __restrict__ s1d) {
    __shared__ char lds[49152];               // Ah 8K | Al 8K | Bh 16K | Bl 16K
    char* ldsAh = lds;
    char* ldsAl = lds + 8192;
    char* ldsBh = lds + 16384;
    char* ldsBl = lds + 32768;
    const int tid = threadIdx.x;
    const int wid = tid >> 6, lane = tid & 63;
    const int wm = wid >> 1, wn = wid & 1;
    const int l15 = lane & 15, lg = lane >> 4;
    const int row0 = blockIdx.x * 64;

    // A-staging geometry: thread t -> row=t>>2, kc=(t&3)*16
    const int arow = tid >> 2;
    const int akc  = (tid & 3) * 16;
    const int asw  = (arow & 7) << 4;
    int agr = row0 + arow; if (agr > NN - 1) agr = NN - 1;
    const float* aptr = X + (long)agr * DIN + akc;

    f32x4 acc[2][4];
    #pragma unroll
    for (int mi = 0; mi < 2; ++mi)
        #pragma unroll
        for (int ni = 0; ni < 4; ++ni) acc[mi][ni] = (f32x4)(0.f);

    for (int k0 = 0; k0 < DIN; k0 += 64) {
        // B: async global->LDS (1024 chunks each of Bh, Bl)
        #pragma unroll
        for (int p = 0; p < 4; ++p) {
            int q = p * 256 + tid;
            int dstoff = (p * 256 + wid * 64) << 4;
            int rr = q >> 3;
            int w = (q & 7) << 4;
            int sw = (rr & 7) << 4;
            long sb = (long)rr * (DIN * 2) + k0 * 2 + (w ^ sw);
            gl16((const char*)BhT + sb, ldsBh + dstoff);
            gl16((const char*)BlT + sb, ldsBl + dstoff);
        }
        // A: reg-stage 16 f32 -> split -> swizzled ds_write (hi/lo)
        {
            f32x4 v0 = *(const f32x4*)(aptr + k0);
            f32x4 v1 = *(const f32x4*)(aptr + k0 + 4);
            f32x4 v2 = *(const f32x4*)(aptr + k0 + 8);
            f32x4 v3 = *(const f32x4*)(aptr + k0 + 12);
            s16x8 h0, l0, h1, l1;
            split8(v0, v1, &h0, &l0);
            split8(v2, v3, &h1, &l1);
            int b0 = arow * 128 + ((akc * 2) ^ asw);
            int b1 = arow * 128 + ((akc * 2 + 16) ^ asw);
            *(s16x8*)(ldsAh + b0) = h0;
            *(s16x8*)(ldsAh + b1) = h1;
            *(s16x8*)(ldsAl + b0) = l0;
            *(s16x8*)(ldsAl + b1) = l1;
        }
        __syncthreads();
        #pragma unroll
        for (int ks = 0; ks < 2; ++ks) {
            s16x8 ah[2], al[2], bh[4], bl[4];
            #pragma unroll
            for (int mi = 0; mi < 2; ++mi) {
                int row = wm * 32 + mi * 16 + l15;
                int sw = (row & 7) << 4;
                int kb = (ks * 32 + lg * 8) * 2;
                ah[mi] = *(const s16x8*)(ldsAh + row * 128 + (kb ^ sw));
                al[mi] = *(const s16x8*)(ldsAl + row * 128 + (kb ^ sw));
            }
            #pragma unroll
            for (int ni = 0; ni < 4; ++ni) {
                int col = wn * 64 + ni * 16 + l15;
                int sw = (col & 7) << 4;
                int kb = (ks * 32 + lg * 8) * 2;
                bh[ni] = *(const s16x8*)(ldsBh + col * 128 + (kb ^ sw));
                bl[ni] = *(const s16x8*)(ldsBl + col * 128 + (kb ^ sw));
            }
            #pragma unroll
            for (int mi = 0; mi < 2; ++mi)
                #pragma unroll
                for (int ni = 0; ni < 4; ++ni) {
                    acc[mi][ni] = __builtin_amdgcn_mfma_f32_16x16x32_bf16(ah[mi], bh[ni], acc[mi][ni], 0, 0, 0);
                    acc[mi][ni] = __builtin_amdgcn_mfma_f32_16x16x32_bf16(ah[mi], bl[ni], acc[mi][ni], 0, 0, 0);
                    acc[mi][ni] = __builtin_amdgcn_mfma_f32_16x16x32_bf16(al[mi], bh[ni], acc[mi][ni], 0, 0, 0);
                }
        }
        __syncthreads();
    }

    // epilogue: store H (C/D layout: col=lane&15, row=(lane>>4)*4+reg)
    #pragma unroll
    for (int mi = 0; mi < 2; ++mi)
        #pragma unroll
        for (int ni = 0; ni < 4; ++ni) {
            int col = wn * 64 + ni * 16 + l15;
            #pragma unroll
            for (int r = 0; r < 4; ++r) {
                int grow = row0 + wm * 32 + mi * 16 + lg * 4 + r;
                if (grow < NN) H[(long)grow * F1 + col] = acc[mi][ni][r];
            }
        }
    // fused per-node scores: head = col>>5 = 2*wn + (ni>>1)
    float av[4], bv[4];
    #pragma unroll
    for (int ni = 0; ni < 4; ++ni) {
        int col = wn * 64 + ni * 16 + l15;
        av[ni] = a_src[col];
        bv[ni] = a_dst[col];
    }
    #pragma unroll
    for (int mi = 0; mi < 2; ++mi)
        #pragma unroll
        for (int hl = 0; hl < 2; ++hl) {
            #pragma unroll
            for (int r = 0; r < 4; ++r) {
                float t1 = acc[mi][2 * hl][r] * av[2 * hl] + acc[mi][2 * hl + 1][r] * av[2 * hl + 1];
                float t2 = acc[mi][2 * hl][r] * bv[2 * hl] + acc[mi][2 * hl + 1][r] * bv[2 * hl + 1];
                #pragma unroll
                for (int o = 1; o < 16; o <<= 1) {
                    t1 += __shfl_xor(t1, o);
                    t2 += __shfl_xor(t2, o);
                }
                int grow = row0 + wm * 32 + mi * 16 + lg * 4 + r;
                if (l15 == 0 && grow < NN) {
                    int head = 2 * wn + hl;
                    s1s[grow * 4 + head] = t1;
                    s1d[grow * 4 + head] = t2;
                }
            }
        }
}

// ---------------- GEMM2 MFMA: [NN,128] x [128,40->48] -> Z, + fused scores ----------------
__global__ __launch_bounds__(256) void gemm2_mfma(const float* __restrict__ H1,
        const unsigned short* __restrict__ B2h, const unsigned short* __restrict__ B2l,
        const float* __restrict__ a_src, const float* __restrict__ a_dst,
        float* __restrict__ Z, float* __restrict__ s2s, float* __restrict__ s2d) {
    __shared__ char lds[57344];               // A 32K | Bh 12K | Bl 12K
    char* ldsA  = lds;
    char* ldsBh = lds + 32768;
    char* ldsBl = lds + 45056;
    const int tid = threadIdx.x;
    const int wid = tid >> 6, lane = tid & 63;
    const int l15 = lane & 15, lg = lane >> 4;
    const int row0 = blockIdx.x * 64;

    #pragma unroll
    for (int p = 0; p < 8; ++p) {
        int q = p * 256 + tid;
        int row = q >> 5;
        int w = (q & 31) << 4;
        int sw = (row & 7) << 4;
        int gr = row0 + row; if (gr > NN - 1) gr = NN - 1;
        gl16((const char*)(H1 + (long)gr * F1) + (w ^ sw), ldsA + ((p * 256 + wid * 64) << 4));
    }
    #pragma unroll
    for (int p = 0; p < 3; ++p) {
        int q = p * 256 + tid;
        int rr = q >> 4;
        int w = (q & 15) << 4;
        int sw = (rr & 7) << 4;
        int dstoff = (p * 256 + wid * 64) << 4;
        gl16((const char*)B2h + rr * 256 + (w ^ sw), ldsBh + dstoff);
        gl16((const char*)B2l + rr * 256 + (w ^ sw), ldsBl + dstoff);
    }
    __syncthreads();

    f32x4 acc[3];
    #pragma unroll
    for (int ni = 0; ni < 3; ++ni) acc[ni] = (f32x4)(0.f);

    #pragma unroll
    for (int ks = 0; ks < 4; ++ks) {
        int row = wid * 16 + l15;
        int sw = (row & 7) << 4;
        int kb = (ks * 32 + lg * 8) * 4;
        f32x4 v0 = *(const f32x4*)(ldsA + row * 512 + ((kb)      ^ sw));
        f32x4 v1 = *(const f32x4*)(ldsA + row * 512 + ((kb + 16) ^ sw));
        s16x8 ah, al;
        split8(v0, v1, &ah, &al);
        #pragma unroll
        for (int ni = 0; ni < 3; ++ni) {
            int cc = ni * 16 + l15;
            int swb = (cc & 7) << 4;
            int kb2 = (ks * 32 + lg * 8) * 2;
            s16x8 bh = *(const s16x8*)(ldsBh + cc * 256 + (kb2 ^ swb));
            s16x8 bl = *(const s16x8*)(ldsBl + cc * 256 + (kb2 ^ swb));
            acc[ni] = __builtin_amdgcn_mfma_f32_16x16x32_bf16(ah, bh, acc[ni], 0, 0, 0);
            acc[ni] = __builtin_amdgcn_mfma_f32_16x16x32_bf16(ah, bl, acc[ni], 0, 0, 0);
            acc[ni] = __builtin_amdgcn_mfma_f32_16x16x32_bf16(al, bh, acc[ni], 0, 0, 0);
        }
    }

    float av[3], bv[3];
    #pragma unroll
    for (int ni = 0; ni < 3; ++ni) {
        int cc = ni * 16 + l15;
        av[ni] = (cc < NC) ? a_src[cc] : 0.f;
        bv[ni] = (cc < NC) ? a_dst[cc] : 0.f;
    }
    #pragma unroll
    for (int r = 0; r < 4; ++r) {
        int grow = row0 + wid * 16 + lg * 4 + r;
        bool ok = grow < NN;
        float t1 = acc[0][r] * av[0] + acc[1][r] * av[1] + acc[2][r] * av[2];
        float t2 = acc[0][r] * bv[0] + acc[1][r] * bv[1] + acc[2][r] * bv[2];
        #pragma unroll
        for (int o = 1; o < 16; o <<= 1) {
            t1 += __shfl_xor(t1, o);
            t2 += __shfl_xor(t2, o);
        }
        #pragma unroll
        for (int ni = 0; ni < 3; ++ni) {
            int cc = ni * 16 + l15;
            if (ok && cc < NC) Z[(long)grow * NC + cc] = acc[ni][r];
        }
        if (ok && l15 == 0) { s2s[grow] = t1; s2d[grow] = t2; }
    }
}

// ------------- fused layer-1 softmax + aggregate + bias + ELU -------------
// wave per dst node; alphas precomputed into LDS; pass 2 = pure gather+FMA.
__global__ __launch_bounds__(256) void fusedagg1_kernel(
        const int* __restrict__ off, const int* __restrict__ ssorted,
        const float* __restrict__ ssrc, const float* __restrict__ sdst,
        const float* __restrict__ H, const float* __restrict__ b,
        float* __restrict__ O) {
    __shared__ int idx_lds[4][CAP];
    __shared__ __align__(16) float e_lds[4][CAP][4];
    const int nd = threadIdx.x >> 6;
    int n = blockIdx.x * 4 + nd;
    if (n >= NN) return;
    const int lane = threadIdx.x & 63;
    const int base = off[n];
    const int deg  = off[n + 1] - base;
    const float4 vd = *(const float4*)(sdst + (long)n * 4);

    // sweep 1: logits -> LDS, track max
    float m0 = -1e30f, m1 = -1e30f, m2 = -1e30f, m3 = -1e30f;
    for (int k = lane; k < deg; k += 64) {
        int s = ssorted[base + k];
        float4 vs = *(const float4*)(ssrc + (long)s * 4);
        float x0 = vs.x + vd.x; x0 = (x0 > 0.f) ? x0 : NEG * x0;
        float x1 = vs.y + vd.y; x1 = (x1 > 0.f) ? x1 : NEG * x1;
        float x2 = vs.z + vd.z; x2 = (x2 > 0.f) ? x2 : NEG * x2;
        float x3 = vs.w + vd.w; x3 = (x3 > 0.f) ? x3 : NEG * x3;
        if (k < CAP) {
            idx_lds[nd][k] = s;
            *(f32x4*)&e_lds[nd][k][0] = (f32x4){x0, x1, x2, x3};
        }
        m0 = fmaxf(m0, x0); m1 = fmaxf(m1, x1);
        m2 = fmaxf(m2, x2); m3 = fmaxf(m3, x3);
    }
    #pragma unroll
    for (int o = 1; o < 64; o <<= 1) {
        m0 = fmaxf(m0, __shfl_xor(m0, o));
        m1 = fmaxf(m1, __shfl_xor(m1, o));
        m2 = fmaxf(m2, __shfl_xor(m2, o));
        m3 = fmaxf(m3, __shfl_xor(m3, o));
    }
    // sweep 2: e = exp(x-m) -> LDS, track sum
    float t0 = 0.f, t1 = 0.f, t2 = 0.f, t3 = 0.f;
    for (int k = lane; k < deg; k += 64) {
        float x0, x1, x2, x3;
        if (k < CAP) {
            f32x4 v = *(const f32x4*)&e_lds[nd][k][0];
            x0 = v.x; x1 = v.y; x2 = v.z; x3 = v.w;
        } else {
            int s = ssorted[base + k];
            float4 vs = *(const float4*)(ssrc + (long)s * 4);
            x0 = vs.x + vd.x; x0 = (x0 > 0.f) ? x0 : NEG * x0;
            x1 = vs.y + vd.y; x1 = (x1 > 0.f) ? x1 : NEG * x1;
            x2 = vs.z + vd.z; x2 = (x2 > 0.f) ? x2 : NEG * x2;
            x3 = vs.w + vd.w; x3 = (x3 > 0.f) ? x3 : NEG * x3;
        }
        float e0 = __expf(x0 - m0), e1 = __expf(x1 - m1);
        float e2 = __expf(x2 - m2), e3 = __expf(x3 - m3);
        if (k < CAP) *(f32x4*)&e_lds[nd][k][0] = (f32x4){e0, e1, e2, e3};
        t0 += e0; t1 += e1; t2 += e2; t3 += e3;
    }
    #pragma unroll
    for (int o = 1; o < 64; o <<= 1) {
        t0 += __shfl_xor(t0, o); t1 += __shfl_xor(t1, o);
        t2 += __shfl_xor(t2, o); t3 += __shfl_xor(t3, o);
    }
    // pass 2: lane L owns feats {2L, 2L+1}, head = L>>4
    const int hd = lane >> 4;
    const float inv = 1.f / (((hd == 0) ? t0 : (hd == 1) ? t1 : (hd == 2) ? t2 : t3) + 1e-9f);
    const float mh  = (hd == 0) ? m0 : (hd == 1) ? m1 : (hd == 2) ? m2 : m3;
    const float vdh = (hd == 0) ? vd.x : (hd == 1) ? vd.y : (hd == 2) ? vd.z : vd.w;
    float acc0 = 0.f, acc1 = 0.f;
    const int kend = (deg < CAP) ? deg : CAP;
    for (int k = 0; k < kend; ++k) {
        int s = idx_lds[nd][k];
        float e = e_lds[nd][k][hd];
        float2 hv = *(const float2*)(H + (long)s * F1 + 2 * lane);
        acc0 += e * hv.x;
        acc1 += e * hv.y;
    }
    for (int k = CAP; k < deg; ++k) {          // statistically never taken
        int s = ssorted[base + k];
        float4 vs = *(const float4*)(ssrc + (long)s * 4);
        float x = ((hd == 0) ? vs.x : (hd == 1) ? vs.y : (hd == 2) ? vs.z : vs.w) + vdh;
        x = (x > 0.f) ? x : NEG * x;
        float e = __expf(x - mh);
        float2 hv = *(const float2*)(H + (long)s * F1 + 2 * lane);
        acc0 += e * hv.x;
        acc1 += e * hv.y;
    }
    float2 bb = *(const float2*)(b + 2 * lane);
    float v0 = acc0 * inv + bb.x;
    float v1 = acc1 * inv + bb.y;
    v0 = (v0 > 0.f) ? v0 : expm1f(v0);
    v1 = (v1 > 0.f) ? v1 : expm1f(v1);
    float2 ov = {v0, v1};
    *(float2*)(O + (long)n * F1 + 2 * lane) = ov;
}

// ------------- fused layer-2 softmax + aggregate + bias + row softmax -------------
__global__ __launch_bounds__(256) void fusedagg2_kernel(
        const int* __restrict__ off, const int* __restrict__ ssorted,
        const float* __restrict__ ssrc, const float* __restrict__ sdst,
        const float* __restrict__ Z, const float* __restrict__ b,
        float* __restrict__ out) {
    __shared__ int   idx_lds[4][CAP];
    __shared__ float e_lds[4][CAP];
    const int nd = threadIdx.x >> 6;
    int n = blockIdx.x * 4 + nd;
    if (n >= NN) return;
    const int lane = threadIdx.x & 63;
    const int base = off[n];
    const int deg  = off[n + 1] - base;
    const float sdn = sdst[n];

    float m = -1e30f;
    for (int k = lane; k < deg; k += 64) {
        int s = ssorted[base + k];
        float x = ssrc[s] + sdn;
        x = (x > 0.f) ? x : NEG * x;
        if (k < CAP) { idx_lds[nd][k] = s; e_lds[nd][k] = x; }
        m = fmaxf(m, x);
    }
    #pragma unroll
    for (int o = 1; o < 64; o <<= 1) m = fmaxf(m, __shfl_xor(m, o));
    float t = 0.f;
    for (int k = lane; k < deg; k += 64) {
        float x;
        if (k < CAP) x = e_lds[nd][k];
        else {
            int s = ssorted[base + k];
            x = ssrc[s] + sdn;
            x = (x > 0.f) ? x : NEG * x;
        }
        float e = __expf(x - m);
        if (k < CAP) e_lds[nd][k] = e;
        t += e;
    }
    #pragma unroll
    for (int o = 1; o < 64; o <<= 1) t += __shfl_xor(t, o);
    const float inv = 1.f / (t + 1e-9f);

    float acc = 0.f;
    const int kend = (deg < CAP) ? deg : CAP;
    const bool act = lane < NC;
    for (int k = 0; k < kend; ++k) {
        int s = idx_lds[nd][k];
        float e = e_lds[nd][k];
        if (act) acc += e * Z[(long)s * NC + lane];
    }
    for (int k = CAP; k < deg; ++k) {          // statistically never taken
        int s = ssorted[base + k];
        float x = ssrc[s] + sdn;
        x = (x > 0.f) ? x : NEG * x;
        float e = __expf(x - m);
        if (act) acc += e * Z[(long)s * NC + lane];
    }
    float v = act ? acc * inv + b[lane] : -1e30f;
    float mx = v;
    #pragma unroll
    for (int o = 32; o > 0; o >>= 1) mx = fmaxf(mx, __shfl_xor(mx, o));
    float e = act ? __expf(v - mx) : 0.f;
    float sum = e;
    #pragma unroll
    for (int o = 32; o > 0; o >>= 1) sum += __shfl_xor(sum, o);
    if (act) out[(long)n * NC + lane] = e / sum;
}

extern "C" void kernel_launch(void* const* d_in, const int* in_sizes, int n_in,
                              void* d_out, int out_size, void* d_ws, size_t ws_size,
                              hipStream_t stream) {
    const float* x      = (const float*)d_in[0];
    const int*   src    = (const int*)  d_in[1];
    const int*   dst    = (const int*)  d_in[2];
    const float* W1     = (const float*)d_in[3];
    const float* a_src1 = (const float*)d_in[4];
    const float* a_dst1 = (const float*)d_in[5];
    const float* b1     = (const float*)d_in[6];
    const float* W2     = (const float*)d_in[7];
    const float* a_src2 = (const float*)d_in[8];
    const float* a_dst2 = (const float*)d_in[9];
    const float* b2     = (const float*)d_in[10];
    float* out = (float*)d_out;

    float* ws   = (float*)d_ws;
    float* hpre = ws;                   // 6,400,000
    float* s1s  = hpre + 6400000;       //   200,000
    float* s1d  = s1s + 200000;         //   200,000
    float* h1   = s1d + 200000;         // 6,400,000
    float* z2   = h1 + 6400000;         // 2,000,000
    float* s2s  = z2 + 2000000;         //    50,000
    float* s2d  = s2s + 50000;          //    50,000
    int*   deg     = (int*)(s2d + 50000);   //  50,000
    int*   off     = deg + 50000;           //  50,008 (padded)
    int*   cur     = off + 50008;           //  50,000
    int*   ssorted = cur + 50000;           // 850,000
    unsigned short* Wh1T = (unsigned short*)(ssorted + 850000); // 65,536
    unsigned short* Wl1T = Wh1T + 65536;                        // 65,536
    unsigned short* Wh2T = Wl1T + 65536;                        //  6,144
    unsigned short* Wl2T = Wh2T + 6144;                         //  6,144

    // CSR build (by dst)
    zero_int_kernel<<<(50000 + 255) / 256, 256, 0, stream>>>(deg, 50000);
    hist_kernel<<<(ET + 255) / 256, 256, 0, stream>>>(dst, deg);
    scan_kernel<<<1, 1024, 0, stream>>>(deg, off, cur);
    scatter_kernel<<<(ET + 255) / 256, 256, 0, stream>>>(src, dst, cur, ssorted);

    // weight splits
    wsplit1_kernel<<<(DIN * F1 + 255) / 256, 256, 0, stream>>>(W1, Wh1T, Wl1T);
    wsplit2_kernel<<<(48 * 128 + 255) / 256, 256, 0, stream>>>(W2, Wh2T, Wl2T);

    // layer 1
    gemm1_mfma<<<(NN + 63) / 64, 256, 0, stream>>>(x, Wh1T, Wl1T, a_src1, a_dst1, hpre, s1s, s1d);
    fusedagg1_kernel<<<(NN + 3) / 4, 256, 0, stream>>>(off, ssorted, s1s, s1d, hpre, b1, h1);

    // layer 2
    gemm2_mfma<<<(NN + 63) / 64, 256, 0, stream>>>(h1, Wh2T, Wl2T, a_src2, a_dst2, z2, s2s, s2d);
    fusedagg2_kernel<<<(NN + 3) / 4, 256, 0, stream>>>(off, ssorted, s2s, s2d, z2, b2, out);
}

// Round 5
// 429.688 us; speedup vs baseline: 2.9099x; 1.2265x over previous
//
#include <hip/hip_runtime.h>
#include <hip/hip_bf16.h>
#include <math.h>

// GAT 2-layer, MI355X. CSR aggregation (LDS-cached alphas) + MFMA GEMMs
// (3-term bf16 split ~ f32 accuracy). Hierarchical CSR scan (r5).
#define NN 50000
#define NE 800000
#define ET 850000          // NE + NN self loops
#define DIN 512
#define F1 128             // HEADS*HIDDEN
#define NC 40
#define NEG 0.2f
#define CAP 128            // per-node cached-edge cap (max degree ~50 stat.)
#define SCAN_NB ((NN + 255) / 256)   // 196

typedef __attribute__((ext_vector_type(8))) short s16x8;
typedef __attribute__((ext_vector_type(4))) float f32x4;

__device__ inline unsigned short bfh(float f) {
    __hip_bfloat16 h = __float2bfloat16(f);
    return __builtin_bit_cast(unsigned short, h);
}
__device__ inline float bff(unsigned short u) {
    unsigned int x = (unsigned int)u << 16;
    return __builtin_bit_cast(float, x);
}

__device__ inline void split8(f32x4 v0, f32x4 v1, s16x8* hi, s16x8* lo) {
    float f[8] = {v0.x, v0.y, v0.z, v0.w, v1.x, v1.y, v1.z, v1.w};
    #pragma unroll
    for (int j = 0; j < 8; ++j) {
        unsigned short h = bfh(f[j]);
        (*hi)[j] = (short)h;
        (*lo)[j] = (short)bfh(f[j] - bff(h));
    }
}

__device__ inline void gl16(const void* g, void* l) {
    __builtin_amdgcn_global_load_lds((const __attribute__((address_space(1))) unsigned int*)g,
                                     (__attribute__((address_space(3))) unsigned int*)l, 16, 0, 0);
}

// ---------------- prep: zero deg + weight splits (merged) ----------------
__global__ void prep_kernel(const float* __restrict__ W1,
        const float* __restrict__ W2, int* __restrict__ deg,
        unsigned short* __restrict__ Wh1T, unsigned short* __restrict__ Wl1T,
        unsigned short* __restrict__ Wh2T, unsigned short* __restrict__ Wl2T) {
    int i = blockIdx.x * blockDim.x + threadIdx.x;
    if (i < NN) deg[i] = 0;
    if (i < DIN * F1) {   // wsplit1: W1 [512][128] -> [128][512] hi/lo
        int k = i >> 7, c = i & 127;
        float w = W1[i];
        unsigned short h = bfh(w);
        unsigned short l = bfh(w - bff(h));
        Wh1T[c * DIN + k] = h;
        Wl1T[c * DIN + k] = l;
    }
    if (i < 48 * 128) {   // wsplit2: W2 [128][40] -> [48][128] hi/lo padded
        int c = i >> 7, k = i & 127;
        float w = (c < NC) ? W2[k * NC + c] : 0.f;
        unsigned short h = bfh(w);
        unsigned short l = bfh(w - bff(h));
        Wh2T[c * 128 + k] = h;
        Wl2T[c * 128 + k] = l;
    }
}

// ---------------- CSR build ----------------
__global__ void hist_kernel(const int* __restrict__ dst, int* __restrict__ deg) {
    int e = blockIdx.x * blockDim.x + threadIdx.x;
    if (e >= ET) return;
    int d = (e < NE) ? dst[e] : (e - NE);
    atomicAdd(&deg[d], 1);
}

__global__ __launch_bounds__(256) void partial_kernel(const int* __restrict__ deg,
        int* __restrict__ bsum) {
    __shared__ int red[4];
    int i = blockIdx.x * 256 + threadIdx.x;
    int v = (i < NN) ? deg[i] : 0;
    #pragma unroll
    for (int o = 1; o < 64; o <<= 1) v += __shfl_xor(v, o);
    if ((threadIdx.x & 63) == 0) red[threadIdx.x >> 6] = v;
    __syncthreads();
    if (threadIdx.x == 0) bsum[blockIdx.x] = red[0] + red[1] + red[2] + red[3];
}

__global__ __launch_bounds__(256) void scanp_kernel(const int* __restrict__ bsum,
        int* __restrict__ bbase) {
    __shared__ int s[256];
    int t = threadIdx.x;
    s[t] = (t < SCAN_NB) ? bsum[t] : 0;
    __syncthreads();
    #pragma unroll
    for (int o = 1; o < 256; o <<= 1) {
        int v = (t >= o) ? s[t - o] : 0;
        __syncthreads();
        s[t] += v;
        __syncthreads();
    }
    if (t < SCAN_NB) bbase[t] = (t == 0) ? 0 : s[t - 1];
}

__global__ __launch_bounds__(256) void emit_kernel(const int* __restrict__ deg,
        const int* __restrict__ bbase, int* __restrict__ off, int* __restrict__ cur) {
    __shared__ int s[256];
    int t = threadIdx.x;
    int i = blockIdx.x * 256 + t;
    int d = (i < NN) ? deg[i] : 0;
    s[t] = d;
    __syncthreads();
    #pragma unroll
    for (int o = 1; o < 256; o <<= 1) {
        int v = (t >= o) ? s[t - o] : 0;
        __syncthreads();
        s[t] += v;
        __syncthreads();
    }
    int o0 = bbase[blockIdx.x] + s[t] - d;   // exclusive
    if (i < NN) { off[i] = o0; cur[i] = o0; }
    if (i == NN - 1) off[NN] = o0 + d;
}

__global__ void scatter_kernel(const int* __restrict__ src, const int* __restrict__ dst,
        int* __restrict__ cur, int* __restrict__ ssorted) {
    int e = blockIdx.x * blockDim.x + threadIdx.x;
    if (e >= ET) return;
    int s = (e < NE) ? src[e] : (e - NE);
    int d = (e < NE) ? dst[e] : (e - NE);
    int pos = atomicAdd(&cur[d], 1);
    ssorted[pos] = s;
}

// ---------------- GEMM1 MFMA: [NN,512] x [512,128] -> hpre, + fused scores ----------------
// block 256 = 4 waves (wm 0..1, wn 0..1), BM=64, BN=128, BK=64, wave tile 32x64.
// A reg-staged + pre-split to bf16 hi/lo in LDS; B via global_load_lds.
__global__ __launch_bounds__(256) void gemm1_mfma(const float* __restrict__ X,
        const unsigned short* __restrict__ BhT, const unsigned short* __restrict__ BlT,
        const float* __restrict__ a_src, const float* __restrict__ a_dst,
        float* __restrict__ H, float* __restrict__ s1s, float* __restrict__ s1d) {
    __shared__ char lds[49152];               // Ah 8K | Al 8K | Bh 16K | Bl 16K
    char* ldsAh = lds;
    char* ldsAl = lds + 8192;
    char* ldsBh = lds + 16384;
    char* ldsBl = lds + 32768;
    const int tid = threadIdx.x;
    const int wid = tid >> 6, lane = tid & 63;
    const int wm = wid >> 1, wn = wid & 1;
    const int l15 = lane & 15, lg = lane >> 4;
    const int row0 = blockIdx.x * 64;

    const int arow = tid >> 2;
    const int akc  = (tid & 3) * 16;
    const int asw  = (arow & 7) << 4;
    int agr = row0 + arow; if (agr > NN - 1) agr = NN - 1;
    const float* aptr = X + (long)agr * DIN + akc;

    f32x4 acc[2][4];
    #pragma unroll
    for (int mi = 0; mi < 2; ++mi)
        #pragma unroll
        for (int ni = 0; ni < 4; ++ni) acc[mi][ni] = (f32x4)(0.f);

    for (int k0 = 0; k0 < DIN; k0 += 64) {
        #pragma unroll
        for (int p = 0; p < 4; ++p) {
            int q = p * 256 + tid;
            int dstoff = (p * 256 + wid * 64) << 4;
            int rr = q >> 3;
            int w = (q & 7) << 4;
            int sw = (rr & 7) << 4;
            long sb = (long)rr * (DIN * 2) + k0 * 2 + (w ^ sw);
            gl16((const char*)BhT + sb, ldsBh + dstoff);
            gl16((const char*)BlT + sb, ldsBl + dstoff);
        }
        {
            f32x4 v0 = *(const f32x4*)(aptr + k0);
            f32x4 v1 = *(const f32x4*)(aptr + k0 + 4);
            f32x4 v2 = *(const f32x4*)(aptr + k0 + 8);
            f32x4 v3 = *(const f32x4*)(aptr + k0 + 12);
            s16x8 h0, l0, h1, l1;
            split8(v0, v1, &h0, &l0);
            split8(v2, v3, &h1, &l1);
            int b0 = arow * 128 + ((akc * 2) ^ asw);
            int b1 = arow * 128 + ((akc * 2 + 16) ^ asw);
            *(s16x8*)(ldsAh + b0) = h0;
            *(s16x8*)(ldsAh + b1) = h1;
            *(s16x8*)(ldsAl + b0) = l0;
            *(s16x8*)(ldsAl + b1) = l1;
        }
        __syncthreads();
        #pragma unroll
        for (int ks = 0; ks < 2; ++ks) {
            s16x8 ah[2], al[2], bh[4], bl[4];
            #pragma unroll
            for (int mi = 0; mi < 2; ++mi) {
                int row = wm * 32 + mi * 16 + l15;
                int sw = (row & 7) << 4;
                int kb = (ks * 32 + lg * 8) * 2;
                ah[mi] = *(const s16x8*)(ldsAh + row * 128 + (kb ^ sw));
                al[mi] = *(const s16x8*)(ldsAl + row * 128 + (kb ^ sw));
            }
            #pragma unroll
            for (int ni = 0; ni < 4; ++ni) {
                int col = wn * 64 + ni * 16 + l15;
                int sw = (col & 7) << 4;
                int kb = (ks * 32 + lg * 8) * 2;
                bh[ni] = *(const s16x8*)(ldsBh + col * 128 + (kb ^ sw));
                bl[ni] = *(const s16x8*)(ldsBl + col * 128 + (kb ^ sw));
            }
            #pragma unroll
            for (int mi = 0; mi < 2; ++mi)
                #pragma unroll
                for (int ni = 0; ni < 4; ++ni) {
                    acc[mi][ni] = __builtin_amdgcn_mfma_f32_16x16x32_bf16(ah[mi], bh[ni], acc[mi][ni], 0, 0, 0);
                    acc[mi][ni] = __builtin_amdgcn_mfma_f32_16x16x32_bf16(ah[mi], bl[ni], acc[mi][ni], 0, 0, 0);
                    acc[mi][ni] = __builtin_amdgcn_mfma_f32_16x16x32_bf16(al[mi], bh[ni], acc[mi][ni], 0, 0, 0);
                }
        }
        __syncthreads();
    }

    #pragma unroll
    for (int mi = 0; mi < 2; ++mi)
        #pragma unroll
        for (int ni = 0; ni < 4; ++ni) {
            int col = wn * 64 + ni * 16 + l15;
            #pragma unroll
            for (int r = 0; r < 4; ++r) {
                int grow = row0 + wm * 32 + mi * 16 + lg * 4 + r;
                if (grow < NN) H[(long)grow * F1 + col] = acc[mi][ni][r];
            }
        }
    float av[4], bv[4];
    #pragma unroll
    for (int ni = 0; ni < 4; ++ni) {
        int col = wn * 64 + ni * 16 + l15;
        av[ni] = a_src[col];
        bv[ni] = a_dst[col];
    }
    #pragma unroll
    for (int mi = 0; mi < 2; ++mi)
        #pragma unroll
        for (int hl = 0; hl < 2; ++hl) {
            #pragma unroll
            for (int r = 0; r < 4; ++r) {
                float t1 = acc[mi][2 * hl][r] * av[2 * hl] + acc[mi][2 * hl + 1][r] * av[2 * hl + 1];
                float t2 = acc[mi][2 * hl][r] * bv[2 * hl] + acc[mi][2 * hl + 1][r] * bv[2 * hl + 1];
                #pragma unroll
                for (int o = 1; o < 16; o <<= 1) {
                    t1 += __shfl_xor(t1, o);
                    t2 += __shfl_xor(t2, o);
                }
                int grow = row0 + wm * 32 + mi * 16 + lg * 4 + r;
                if (l15 == 0 && grow < NN) {
                    int head = 2 * wn + hl;
                    s1s[grow * 4 + head] = t1;
                    s1d[grow * 4 + head] = t2;
                }
            }
        }
}

// ---------------- GEMM2 MFMA: [NN,128] x [128,40->48] -> Z, + fused scores ----------------
__global__ __launch_bounds__(256) void gemm2_mfma(const float* __restrict__ H1,
        const unsigned short* __restrict__ B2h, const unsigned short* __restrict__ B2l,
        const float* __restrict__ a_src, const float* __restrict__ a_dst,
        float* __restrict__ Z, float* __restrict__ s2s, float* __restrict__ s2d) {
    __shared__ char lds[57344];               // A 32K | Bh 12K | Bl 12K
    char* ldsA  = lds;
    char* ldsBh = lds + 32768;
    char* ldsBl = lds + 45056;
    const int tid = threadIdx.x;
    const int wid = tid >> 6, lane = tid & 63;
    const int l15 = lane & 15, lg = lane >> 4;
    const int row0 = blockIdx.x * 64;

    #pragma unroll
    for (int p = 0; p < 8; ++p) {
        int q = p * 256 + tid;
        int row = q >> 5;
        int w = (q & 31) << 4;
        int sw = (row & 7) << 4;
        int gr = row0 + row; if (gr > NN - 1) gr = NN - 1;
        gl16((const char*)(H1 + (long)gr * F1) + (w ^ sw), ldsA + ((p * 256 + wid * 64) << 4));
    }
    #pragma unroll
    for (int p = 0; p < 3; ++p) {
        int q = p * 256 + tid;
        int rr = q >> 4;
        int w = (q & 15) << 4;
        int sw = (rr & 7) << 4;
        int dstoff = (p * 256 + wid * 64) << 4;
        gl16((const char*)B2h + rr * 256 + (w ^ sw), ldsBh + dstoff);
        gl16((const char*)B2l + rr * 256 + (w ^ sw), ldsBl + dstoff);
    }
    __syncthreads();

    f32x4 acc[3];
    #pragma unroll
    for (int ni = 0; ni < 3; ++ni) acc[ni] = (f32x4)(0.f);

    #pragma unroll
    for (int ks = 0; ks < 4; ++ks) {
        int row = wid * 16 + l15;
        int sw = (row & 7) << 4;
        int kb = (ks * 32 + lg * 8) * 4;
        f32x4 v0 = *(const f32x4*)(ldsA + row * 512 + ((kb)      ^ sw));
        f32x4 v1 = *(const f32x4*)(ldsA + row * 512 + ((kb + 16) ^ sw));
        s16x8 ah, al;
        split8(v0, v1, &ah, &al);
        #pragma unroll
        for (int ni = 0; ni < 3; ++ni) {
            int cc = ni * 16 + l15;
            int swb = (cc & 7) << 4;
            int kb2 = (ks * 32 + lg * 8) * 2;
            s16x8 bh = *(const s16x8*)(ldsBh + cc * 256 + (kb2 ^ swb));
            s16x8 bl = *(const s16x8*)(ldsBl + cc * 256 + (kb2 ^ swb));
            acc[ni] = __builtin_amdgcn_mfma_f32_16x16x32_bf16(ah, bh, acc[ni], 0, 0, 0);
            acc[ni] = __builtin_amdgcn_mfma_f32_16x16x32_bf16(ah, bl, acc[ni], 0, 0, 0);
            acc[ni] = __builtin_amdgcn_mfma_f32_16x16x32_bf16(al, bh, acc[ni], 0, 0, 0);
        }
    }

    float av[3], bv[3];
    #pragma unroll
    for (int ni = 0; ni < 3; ++ni) {
        int cc = ni * 16 + l15;
        av[ni] = (cc < NC) ? a_src[cc] : 0.f;
        bv[ni] = (cc < NC) ? a_dst[cc] : 0.f;
    }
    #pragma unroll
    for (int r = 0; r < 4; ++r) {
        int grow = row0 + wid * 16 + lg * 4 + r;
        bool ok = grow < NN;
        float t1 = acc[0][r] * av[0] + acc[1][r] * av[1] + acc[2][r] * av[2];
        float t2 = acc[0][r] * bv[0] + acc[1][r] * bv[1] + acc[2][r] * bv[2];
        #pragma unroll
        for (int o = 1; o < 16; o <<= 1) {
            t1 += __shfl_xor(t1, o);
            t2 += __shfl_xor(t2, o);
        }
        #pragma unroll
        for (int ni = 0; ni < 3; ++ni) {
            int cc = ni * 16 + l15;
            if (ok && cc < NC) Z[(long)grow * NC + cc] = acc[ni][r];
        }
        if (ok && l15 == 0) { s2s[grow] = t1; s2d[grow] = t2; }
    }
}

// ------------- fused layer-1 softmax + aggregate + bias + ELU -------------
__global__ __launch_bounds__(256) void fusedagg1_kernel(
        const int* __restrict__ off, const int* __restrict__ ssorted,
        const float* __restrict__ ssrc, const float* __restrict__ sdst,
        const float* __restrict__ H, const float* __restrict__ b,
        float* __restrict__ O) {
    __shared__ int idx_lds[4][CAP];
    __shared__ __align__(16) float e_lds[4][CAP][4];
    const int nd = threadIdx.x >> 6;
    int n = blockIdx.x * 4 + nd;
    if (n >= NN) return;
    const int lane = threadIdx.x & 63;
    const int base = off[n];
    const int deg  = off[n + 1] - base;
    const float4 vd = *(const float4*)(sdst + (long)n * 4);

    float m0 = -1e30f, m1 = -1e30f, m2 = -1e30f, m3 = -1e30f;
    for (int k = lane; k < deg; k += 64) {
        int s = ssorted[base + k];
        float4 vs = *(const float4*)(ssrc + (long)s * 4);
        float x0 = vs.x + vd.x; x0 = (x0 > 0.f) ? x0 : NEG * x0;
        float x1 = vs.y + vd.y; x1 = (x1 > 0.f) ? x1 : NEG * x1;
        float x2 = vs.z + vd.z; x2 = (x2 > 0.f) ? x2 : NEG * x2;
        float x3 = vs.w + vd.w; x3 = (x3 > 0.f) ? x3 : NEG * x3;
        if (k < CAP) {
            idx_lds[nd][k] = s;
            *(f32x4*)&e_lds[nd][k][0] = (f32x4){x0, x1, x2, x3};
        }
        m0 = fmaxf(m0, x0); m1 = fmaxf(m1, x1);
        m2 = fmaxf(m2, x2); m3 = fmaxf(m3, x3);
    }
    #pragma unroll
    for (int o = 1; o < 64; o <<= 1) {
        m0 = fmaxf(m0, __shfl_xor(m0, o));
        m1 = fmaxf(m1, __shfl_xor(m1, o));
        m2 = fmaxf(m2, __shfl_xor(m2, o));
        m3 = fmaxf(m3, __shfl_xor(m3, o));
    }
    float t0 = 0.f, t1 = 0.f, t2 = 0.f, t3 = 0.f;
    for (int k = lane; k < deg; k += 64) {
        float x0, x1, x2, x3;
        if (k < CAP) {
            f32x4 v = *(const f32x4*)&e_lds[nd][k][0];
            x0 = v.x; x1 = v.y; x2 = v.z; x3 = v.w;
        } else {
            int s = ssorted[base + k];
            float4 vs = *(const float4*)(ssrc + (long)s * 4);
            x0 = vs.x + vd.x; x0 = (x0 > 0.f) ? x0 : NEG * x0;
            x1 = vs.y + vd.y; x1 = (x1 > 0.f) ? x1 : NEG * x1;
            x2 = vs.z + vd.z; x2 = (x2 > 0.f) ? x2 : NEG * x2;
            x3 = vs.w + vd.w; x3 = (x3 > 0.f) ? x3 : NEG * x3;
        }
        float e0 = __expf(x0 - m0), e1 = __expf(x1 - m1);
        float e2 = __expf(x2 - m2), e3 = __expf(x3 - m3);
        if (k < CAP) *(f32x4*)&e_lds[nd][k][0] = (f32x4){e0, e1, e2, e3};
        t0 += e0; t1 += e1; t2 += e2; t3 += e3;
    }
    #pragma unroll
    for (int o = 1; o < 64; o <<= 1) {
        t0 += __shfl_xor(t0, o); t1 += __shfl_xor(t1, o);
        t2 += __shfl_xor(t2, o); t3 += __shfl_xor(t3, o);
    }
    const int hd = lane >> 4;
    const float inv = 1.f / (((hd == 0) ? t0 : (hd == 1) ? t1 : (hd == 2) ? t2 : t3) + 1e-9f);
    const float mh  = (hd == 0) ? m0 : (hd == 1) ? m1 : (hd == 2) ? m2 : m3;
    const float vdh = (hd == 0) ? vd.x : (hd == 1) ? vd.y : (hd == 2) ? vd.z : vd.w;
    float acc0 = 0.f, acc1 = 0.f;
    const int kend = (deg < CAP) ? deg : CAP;
    for (int k = 0; k < kend; ++k) {
        int s = idx_lds[nd][k];
        float e = e_lds[nd][k][hd];
        float2 hv = *(const float2*)(H + (long)s * F1 + 2 * lane);
        acc0 += e * hv.x;
        acc1 += e * hv.y;
    }
    for (int k = CAP; k < deg; ++k) {          // statistically never taken
        int s = ssorted[base + k];
        float4 vs = *(const float4*)(ssrc + (long)s * 4);
        float x = ((hd == 0) ? vs.x : (hd == 1) ? vs.y : (hd == 2) ? vs.z : vs.w) + vdh;
        x = (x > 0.f) ? x : NEG * x;
        float e = __expf(x - mh);
        float2 hv = *(const float2*)(H + (long)s * F1 + 2 * lane);
        acc0 += e * hv.x;
        acc1 += e * hv.y;
    }
    float2 bb = *(const float2*)(b + 2 * lane);
    float v0 = acc0 * inv + bb.x;
    float v1 = acc1 * inv + bb.y;
    v0 = (v0 > 0.f) ? v0 : expm1f(v0);
    v1 = (v1 > 0.f) ? v1 : expm1f(v1);
    float2 ov = {v0, v1};
    *(float2*)(O + (long)n * F1 + 2 * lane) = ov;
}

// ------------- fused layer-2 softmax + aggregate + bias + row softmax -------------
__global__ __launch_bounds__(256) void fusedagg2_kernel(
        const int* __restrict__ off, const int* __restrict__ ssorted,
        const float* __restrict__ ssrc, const float* __restrict__ sdst,
        const float* __restrict__ Z, const float* __restrict__ b,
        float* __restrict__ out) {
    __shared__ int   idx_lds[4][CAP];
    __shared__ float e_lds[4][CAP];
    const int nd = threadIdx.x >> 6;
    int n = blockIdx.x * 4 + nd;
    if (n >= NN) return;
    const int lane = threadIdx.x & 63;
    const int base = off[n];
    const int deg  = off[n + 1] - base;
    const float sdn = sdst[n];

    float m = -1e30f;
    for (int k = lane; k < deg; k += 64) {
        int s = ssorted[base + k];
        float x = ssrc[s] + sdn;
        x = (x > 0.f) ? x : NEG * x;
        if (k < CAP) { idx_lds[nd][k] = s; e_lds[nd][k] = x; }
        m = fmaxf(m, x);
    }
    #pragma unroll
    for (int o = 1; o < 64; o <<= 1) m = fmaxf(m, __shfl_xor(m, o));
    float t = 0.f;
    for (int k = lane; k < deg; k += 64) {
        float x;
        if (k < CAP) x = e_lds[nd][k];
        else {
            int s = ssorted[base + k];
            x = ssrc[s] + sdn;
            x = (x > 0.f) ? x : NEG * x;
        }
        float e = __expf(x - m);
        if (k < CAP) e_lds[nd][k] = e;
        t += e;
    }
    #pragma unroll
    for (int o = 1; o < 64; o <<= 1) t += __shfl_xor(t, o);
    const float inv = 1.f / (t + 1e-9f);

    float acc = 0.f;
    const int kend = (deg < CAP) ? deg : CAP;
    const bool act = lane < NC;
    for (int k = 0; k < kend; ++k) {
        int s = idx_lds[nd][k];
        float e = e_lds[nd][k];
        if (act) acc += e * Z[(long)s * NC + lane];
    }
    for (int k = CAP; k < deg; ++k) {          // statistically never taken
        int s = ssorted[base + k];
        float x = ssrc[s] + sdn;
        x = (x > 0.f) ? x : NEG * x;
        float e = __expf(x - m);
        if (act) acc += e * Z[(long)s * NC + lane];
    }
    float v = act ? acc * inv + b[lane] : -1e30f;
    float mx = v;
    #pragma unroll
    for (int o = 32; o > 0; o >>= 1) mx = fmaxf(mx, __shfl_xor(mx, o));
    float e = act ? __expf(v - mx) : 0.f;
    float sum = e;
    #pragma unroll
    for (int o = 32; o > 0; o >>= 1) sum += __shfl_xor(sum, o);
    if (act) out[(long)n * NC + lane] = e / sum;
}

extern "C" void kernel_launch(void* const* d_in, const int* in_sizes, int n_in,
                              void* d_out, int out_size, void* d_ws, size_t ws_size,
                              hipStream_t stream) {
    const float* x      = (const float*)d_in[0];
    const int*   src    = (const int*)  d_in[1];
    const int*   dst    = (const int*)  d_in[2];
    const float* W1     = (const float*)d_in[3];
    const float* a_src1 = (const float*)d_in[4];
    const float* a_dst1 = (const float*)d_in[5];
    const float* b1     = (const float*)d_in[6];
    const float* W2     = (const float*)d_in[7];
    const float* a_src2 = (const float*)d_in[8];
    const float* a_dst2 = (const float*)d_in[9];
    const float* b2     = (const float*)d_in[10];
    float* out = (float*)d_out;

    float* ws   = (float*)d_ws;
    float* hpre = ws;                   // 6,400,000
    float* s1s  = hpre + 6400000;       //   200,000
    float* s1d  = s1s + 200000;         //   200,000
    float* h1   = s1d + 200000;         // 6,400,000
    float* z2   = h1 + 6400000;         // 2,000,000
    float* s2s  = z2 + 2000000;         //    50,000
    float* s2d  = s2s + 50000;          //    50,000
    int*   deg     = (int*)(s2d + 50000);   //  50,000
    int*   off     = deg + 50000;           //  50,008 (padded)
    int*   cur     = off + 50008;           //  50,000
    int*   ssorted = cur + 50000;           // 850,000
    int*   bsum    = ssorted + 850000;      //     256
    int*   bbase   = bsum + 256;            //     256
    unsigned short* Wh1T = (unsigned short*)(bbase + 256);      // 65,536
    unsigned short* Wl1T = Wh1T + 65536;                        // 65,536
    unsigned short* Wh2T = Wl1T + 65536;                        //  6,144
    unsigned short* Wl2T = Wh2T + 6144;                         //  6,144

    // prep: zero deg + weight splits
    prep_kernel<<<(DIN * F1 + 255) / 256, 256, 0, stream>>>(W1, W2, deg, Wh1T, Wl1T, Wh2T, Wl2T);

    // CSR build (by dst): hist -> hierarchical scan -> scatter
    hist_kernel<<<(ET + 255) / 256, 256, 0, stream>>>(dst, deg);
    partial_kernel<<<SCAN_NB, 256, 0, stream>>>(deg, bsum);
    scanp_kernel<<<1, 256, 0, stream>>>(bsum, bbase);
    emit_kernel<<<SCAN_NB, 256, 0, stream>>>(deg, bbase, off, cur);
    scatter_kernel<<<(ET + 255) / 256, 256, 0, stream>>>(src, dst, cur, ssorted);

    // layer 1
    gemm1_mfma<<<(NN + 63) / 64, 256, 0, stream>>>(x, Wh1T, Wl1T, a_src1, a_dst1, hpre, s1s, s1d);
    fusedagg1_kernel<<<(NN + 3) / 4, 256, 0, stream>>>(off, ssorted, s1s, s1d, hpre, b1, h1);

    // layer 2
    gemm2_mfma<<<(NN + 63) / 64, 256, 0, stream>>>(h1, Wh2T, Wl2T, a_src2, a_dst2, z2, s2s, s2d);
    fusedagg2_kernel<<<(NN + 3) / 4, 256, 0, stream>>>(off, ssorted, s2s, s2d, z2, b2, out);
}